// Round 13
// baseline (1183.386 us; speedup 1.0000x reference)
//
#include <hip/hip_runtime.h>
#include <hip/hip_bf16.h>
#include <math.h>

#define B_ 2
#define K_ 2
#define NN_ 4096
#define T_ 8
#define C_ 3
#define H_ 192
#define S_ 1638
#define KK_ 16
#define E_ (S_*KK_)          // 26208
#define NROW (B_*K_*S_)      // 6552
#define SHARP_ 5.0f
#define NT_ 410              // 16-row tiles (last has 8 rows)
#define NAGG_BLKS 3280       // 8 XCD-lanes x 410 pair-slots (4 idle)

typedef __hip_bfloat16 bf;
typedef unsigned long long ull;
typedef __bf16 bf16x8 __attribute__((ext_vector_type(8)));
typedef float f32x4 __attribute__((ext_vector_type(4)));

__device__ int   g_isbf16;
__device__ __align__(16) float g_var[B_*NN_];
__device__ __align__(16) float g_vs1[B_*16];
__device__ __align__(16) float g_vs2[B_*16];
__device__ __align__(16) int   g_topidx[B_*S_];
__device__ __align__(16) float g_possel[B_*S_*3];
__device__ __align__(16) float g_masksel[B_*S_];
__device__ __align__(16) float g_x0[NROW*10];
__device__ __align__(16) int   g_knn[B_*E_];
__device__ __align__(16) float g_ea[B_*E_*4];
__device__ __align__(16) int   g_indeg[B_*S_];
__device__ __align__(16) int   g_cursor[B_*S_];
__device__ __align__(16) int   g_off[B_*(S_+1)];
__device__ __align__(16) int   g_list[B_*E_];
__device__ __align__(16) float g_P[(size_t)NROW*H_];
__device__ __align__(16) bf    g_Qbf[2*(size_t)NROW*H_];   // ping-pong: layer l reads l&1, writes (l+1)&1
__device__ __align__(16) float g_h[(size_t)NROW*H_];
__device__ __align__(16) bf    g_abf[(size_t)NROW*H_];
__device__ __align__(16) bf    g_w2p[(size_t)11*H_*H_];
__device__ __align__(16) bf    g_wcp[(size_t)9*H_*384];
__device__ __align__(16) int   g_tdone[10*NT_];            // per-layer tile counters

__device__ __forceinline__ float bf2f(bf x){ return __bfloat162float(x); }
__device__ __forceinline__ float LD(const void* p, long i){
  return g_isbf16 ? __bfloat162float(((const bf*)p)[i]) : ((const float*)p)[i];
}
__device__ __forceinline__ float LDi(const void* p, long i, int isb){
  return isb ? __bfloat162float(((const bf*)p)[i]) : ((const float*)p)[i];
}
// gelu with branchless A&S 7.1.26 erf (max abs err 1.5e-7; invisible vs bf16 rounding floor)
__device__ __forceinline__ float gelu_f(float x){
  float ax = fabsf(x)*0.70710678118654752f;
  float t = 1.0f/(1.0f + 0.3275911f*ax);
  float p = t*(0.254829592f + t*(-0.284496736f + t*(1.421413741f + t*(-1.453152027f + t*1.061405429f))));
  float er = 1.0f - p*__expf(-ax*ax);
  er = copysignf(er, x);
  return 0.5f*x*(1.0f + er);
}

// ---------------- var_pp (np pairwise-8 semantics) + fused dtype-detect + state zeroing ----------------
__global__ __launch_bounds__(256) void k_var(const void* __restrict__ vel,
                                             const void* __restrict__ ub,
                                             const void* __restrict__ pos){
  __shared__ int s_bad;
  int b = blockIdx.y;
  int bx = blockIdx.x;
  int tid = threadIdx.x;
  if (tid == 0) s_bad = 0;
  __syncthreads();
  {
    const bf* pa = (const bf*)ub; const bf* pb = (const bf*)pos; const bf* pc = (const bf*)vel;
    int bad = 0;
    #pragma unroll
    for (int s = 0; s < 2; ++s){
      float va = __bfloat162float(pa[tid + s*256]);
      float vb = __bfloat162float(pb[tid + s*256]);
      float vc = __bfloat162float(pc[tid + s*256]);
      if (!(fabsf(va) <= 1000.f)) bad = 1;
      if (!(fabsf(vb) <= 1000.f)) bad = 1;
      if (!(fabsf(vc) <= 1000.f)) bad = 1;
    }
    if (bad) atomicOr(&s_bad, 1);
  }
  __syncthreads();
  int isb = (s_bad == 0) ? 1 : 0;
  if (bx == 0 && b == 0 && tid == 0) g_isbf16 = isb;
  int zi = (b*16 + bx)*256 + tid;
  if (zi < B_*S_){ g_indeg[zi] = 0; g_cursor[zi] = 0; }
  if (zi < 10*NT_) g_tdone[zi] = 0;
  int n = bx*256 + tid;
  float v = 0.f;
  #pragma unroll
  for (int c = 0; c < 3; ++c){
    float x[8];
    #pragma unroll
    for (int t = 0; t < 8; ++t)
      x[t] = LDi(vel, ((long)(b*T_+t)*NN_ + n)*3 + c, isb);
    float m = __fadd_rn(__fadd_rn(__fadd_rn(x[0],x[1]), __fadd_rn(x[2],x[3])),
                        __fadd_rn(__fadd_rn(x[4],x[5]), __fadd_rn(x[6],x[7]))) / 8.0f;
    float d[8];
    #pragma unroll
    for (int t = 0; t < 8; ++t){ float dd = __fadd_rn(x[t], -m); d[t] = __fmul_rn(dd,dd); }
    float sv = __fadd_rn(__fadd_rn(__fadd_rn(d[0],d[1]), __fadd_rn(d[2],d[3])),
                         __fadd_rn(__fadd_rn(d[4],d[5]), __fadd_rn(d[6],d[7])));
    v = __fadd_rn(v, sv / 7.0f);
  }
  g_var[b*NN_ + n] = v;
  float s1 = v, s2 = v*v;
  #pragma unroll
  for (int o = 32; o; o >>= 1){ s1 += __shfl_xor(s1,o,64); s2 += __shfl_xor(s2,o,64); }
  __shared__ float r1[4], r2[4];
  int lane = tid & 63, wid = tid >> 6;
  if (!lane){ r1[wid]=s1; r2[wid]=s2; }
  __syncthreads();
  if (tid == 0){
    g_vs1[b*16 + bx] = r1[0]+r1[1]+r1[2]+r1[3];
    g_vs2[b*16 + bx] = r2[0]+r2[1]+r2[2]+r2[3];
  }
}

// ---------------- stable rank-based top-S: one wave per node; also emit compact possel ----------------
__global__ __launch_bounds__(256) void k_rank(const void* __restrict__ pos){
  int b = blockIdx.y;
  int i = blockIdx.x*4 + (threadIdx.x >> 6);
  int lane = threadIdx.x & 63;
  float vi = g_var[b*NN_+i];
  int rank = 0;
  for (int j = lane; j < NN_; j += 64){
    float vj = g_var[b*NN_+j];
    rank += ((vj > vi) || (vj == vi && j < i)) ? 1 : 0;
  }
  #pragma unroll
  for (int o = 32; o; o >>= 1) rank += __shfl_xor(rank, o, 64);
  if (lane == 0 && rank < S_){
    g_topidx[b*S_ + rank] = i;
    long gi = (long)(b*S_ + rank)*3;
    g_possel[gi+0] = LD(pos, ((long)b*NN_+i)*3+0);
    g_possel[gi+1] = LD(pos, ((long)b*NN_+i)*3+1);
    g_possel[gi+2] = LD(pos, ((long)b*NN_+i)*3+2);
  }
}

// ---------------- merged: gather + soft-mask (blocks 0..6) | KNN (blocks 7..) ----------------
#define GATH_BLKS 7
__global__ __launch_bounds__(256) void k_knngather(const void* __restrict__ pos,
                                                   const void* __restrict__ ub,
                                                   const void* __restrict__ vel,
                                                   const void* __restrict__ air){
  int b = blockIdx.y;
  int bx = blockIdx.x;
  if (bx < GATH_BLKS){
    int s = bx*256 + threadIdx.x;
    if (s >= S_) return;
    int gi = b*S_ + s;
    int node = g_topidx[gi];
    float px = g_possel[(long)gi*3+0];
    float py = g_possel[(long)gi*3+1];
    float pz = g_possel[(long)gi*3+2];
    float S1 = 0.f, S2 = 0.f;
    #pragma unroll
    for (int t = 0; t < 16; ++t){ S1 += g_vs1[b*16+t]; S2 += g_vs2[b*16+t]; }
    float mean = S1*(1.f/NN_);
    float sd = sqrtf(fmaxf((S2 - S1*S1*(1.f/NN_))*(1.f/(NN_-1)), 0.f));
    float vf = g_var[b*NN_+node];
    float z = (vf-mean)/(sd+1e-8f);
    float sig = 1.f/(1.f+expf(-SHARP_*z));
    g_masksel[gi] = sig*(1.f - LD(air, b*NN_+node));
    float vl0 = LD(vel, ((long)(b*T_+7)*NN_+node)*3+0);
    float vl1 = LD(vel, ((long)(b*T_+7)*NN_+node)*3+1);
    float vl2 = LD(vel, ((long)(b*T_+7)*NN_+node)*3+2);
    for (int k = 0; k < K_; ++k){
      long row = (long)(b*K_+k)*S_ + s;
      float* x = g_x0 + row*10;
      x[0]=LD(ub, ((long)(b*K_+k)*NN_+node)*3+0);
      x[1]=LD(ub, ((long)(b*K_+k)*NN_+node)*3+1);
      x[2]=LD(ub, ((long)(b*K_+k)*NN_+node)*3+2);
      x[3]=vl0; x[4]=vl1; x[5]=vl2;
      x[6]=px;  x[7]=py;  x[8]=pz;
      x[9]=vf;
    }
    return;
  }
  // ---- KNN: one wave per query node, LDS staged linearly from compact possel
  __shared__ float px[S_], py[S_], pz[S_];
  int j = (bx - GATH_BLKS)*4 + (threadIdx.x >> 6);
  int lane = threadIdx.x & 63;
  for (int t = threadIdx.x; t < S_; t += 256){
    long gi = (long)(b*S_ + t)*3;
    px[t] = g_possel[gi+0];
    py[t] = g_possel[gi+1];
    pz[t] = g_possel[gi+2];
  }
  __syncthreads();
  if (j >= S_) return;
  float xj=px[j], yj=py[j], zj=pz[j];
  float dist[KK_]; int id[KK_];
  #pragma unroll
  for (int t = 0; t < KK_; ++t){ dist[t]=3.0e38f; id[t]=0x7fffffff; }
  for (int c = lane; c < S_; c += 64){
    if (c == j) continue;
    float dx=__fadd_rn(px[c],-xj), dy=__fadd_rn(py[c],-yj), dz=__fadd_rn(pz[c],-zj);
    float d2 = __fadd_rn(__fadd_rn(__fmul_rn(dx,dx), __fmul_rn(dy,dy)), __fmul_rn(dz,dz));
    if (d2 < dist[KK_-1]){
      int p = 0;
      #pragma unroll
      for (int q = 0; q < KK_; ++q) p += (dist[q] <= d2) ? 1 : 0;
      #pragma unroll
      for (int q = KK_-1; q >= 1; --q){
        bool mv = (q > p);
        dist[q] = mv ? dist[q-1] : dist[q];
        id[q]   = mv ? id[q-1]   : id[q];
      }
      #pragma unroll
      for (int q = 0; q < KK_; ++q){ if (q == p){ dist[q] = d2; id[q] = c; } }
    }
  }
  // 16 extraction rounds: f32 min, then min-id among dist ties (== u64 (dist,id) min for dist>=0)
  unsigned selid = 0;
  #pragma unroll
  for (int t = 0; t < KK_; ++t){
    float mv = dist[0];
    #pragma unroll
    for (int o = 32; o; o >>= 1) mv = fminf(mv, __shfl_xor(mv, o, 64));
    unsigned cand = (dist[0] == mv) ? (unsigned)id[0] : 0xFFFFFFFFu;
    #pragma unroll
    for (int o = 32; o; o >>= 1){
      unsigned other = (unsigned)__shfl_xor((int)cand, o, 64);
      cand = (cand < other) ? cand : other;
    }
    if (dist[0] == mv && (unsigned)id[0] == cand){
      #pragma unroll
      for (int q = 0; q < KK_-1; ++q){ dist[q]=dist[q+1]; id[q]=id[q+1]; }
      dist[KK_-1] = 3.0e38f; id[KK_-1] = 0x7fffffff;
    }
    if (lane == t) selid = cand;
  }
  if (lane < KK_){
    int i = (int)selid;
    g_knn[(b*S_+j)*KK_ + lane] = i;
    float rx = __fadd_rn(px[i],-xj), ry = __fadd_rn(py[i],-yj), rz = __fadd_rn(pz[i],-zj);
    float dd = sqrtf(__fadd_rn(__fadd_rn(__fmul_rn(rx,rx), __fmul_rn(ry,ry)), __fmul_rn(rz,rz)));
    float* o = g_ea + ((long)b*E_ + j*KK_ + lane)*4;
    o[0]=rx; o[1]=ry; o[2]=rz; o[3]=dd;
    atomicAdd(&g_indeg[b*S_+i], 1);
  }
}

__global__ void k_scan(){
  __shared__ int sA[2048], sB[2048];
  int b = blockIdx.x, tid = threadIdx.x;   // 1024
  for (int i = tid; i < 2048; i += 1024) sA[i] = (i < S_) ? g_indeg[b*S_+i] : 0;
  __syncthreads();
  int *src = sA, *dst = sB;
  for (int d = 1; d < 2048; d <<= 1){
    for (int i = tid; i < 2048; i += 1024) dst[i] = src[i] + (i >= d ? src[i-d] : 0);
    __syncthreads();
    int* t2 = src; src = dst; dst = t2;
  }
  if (tid == 0) g_off[b*(S_+1)] = 0;
  for (int i = tid; i < S_; i += 1024) g_off[b*(S_+1)+i+1] = src[i];
}

// ---------------- fused setup: weight packing + output init + CSR fill + conv0 projection ----------------
#define PW2_BLKS 1584
#define PWC_BLKS 2592
#define INIT_BLKS 192
#define FILL_BLKS 205
#define PROJ_BLKS 410
__global__ void k_packall(const void* __restrict__ c0w2, const void* __restrict__ cw2,
                          const void* __restrict__ hw1, const void* __restrict__ cw1,
                          const void* __restrict__ ub, const void* __restrict__ air,
                          float* __restrict__ out, const void* __restrict__ c0w1){
  int blk = blockIdx.x;
  if (blk < PW2_BLKS){
    int gi = blk*256 + threadIdx.x;
    if (gi >= 11*H_*H_) return;
    int mat = gi / (H_*H_), r = gi - mat*(H_*H_);
    int k = r / H_, n = r - (r/H_)*H_;
    float v;
    if (mat == 0)      v = LD(c0w2, (long)k*H_ + n);
    else if (mat <= 9) v = LD(cw2, (long)(mat-1)*H_*H_ + (long)k*H_ + n);
    else               v = LD(hw1, (long)k*H_ + n);
    int t = k>>5, q = (k>>3)&3, jj = k&7;
    g_w2p[(size_t)mat*H_*H_ + (((t*4+q)*H_ + n)*8 + jj)] = __float2bfloat16(v);
  } else if (blk < PW2_BLKS + PWC_BLKS){
    int gi = (blk - PW2_BLKS)*256 + threadIdx.x;
    if (gi >= 9*H_*384) return;
    int l = gi / (H_*384), r = gi - l*(H_*384);
    int k = r / 384, n = r - (r/384)*384;
    long base = (long)l*388*H_;
    float v;
    if (n < H_) v = LD(cw1, base + (long)k*H_ + n) - LD(cw1, base + (long)(H_+k)*H_ + n);
    else        v = LD(cw1, base + (long)(H_+k)*H_ + (n-H_));
    int t = k>>5, q = (k>>3)&3, jj = k&7;
    g_wcp[(size_t)l*(H_*384) + (((t*4+q)*384 + n)*8 + jj)] = __float2bfloat16(v);
  } else if (blk < PW2_BLKS + PWC_BLKS + INIT_BLKS){
    int gi = (blk - PW2_BLKS - PWC_BLKS)*256 + threadIdx.x;   // 49152
    int n = (gi/3) % NN_;
    int b = gi / (K_*NN_*C_);
    float a = 1.f - LD(air, b*NN_+n);
    out[gi] = LD(ub, gi) * a;
  } else if (blk < PW2_BLKS + PWC_BLKS + INIT_BLKS + FILL_BLKS){
    int idx = (blk - PW2_BLKS - PWC_BLKS - INIT_BLKS)*256 + threadIdx.x;
    if (idx >= B_*E_) return;
    int b = idx / E_, e = idx - b*E_;
    int i = g_knn[idx];
    int slot = atomicAdd(&g_cursor[b*S_+i], 1);
    g_list[b*E_ + g_off[b*(S_+1)+i] + slot] = e;
  } else {
    // conv0 node projection (K=10), weights in LDS; writes Q buffer 0
    __shared__ float xs[16][10];
    __shared__ float wP[10][192];
    __shared__ float wQ[10][192];
    int tid = threadIdx.x;
    long rowBase = (long)(blk - PW2_BLKS - PWC_BLKS - INIT_BLKS - FILL_BLKS) * 16;
    for (int idx = tid; idx < 1920; idx += 256){
      int f = idx / 192, n = idx - (idx/192)*192;
      float a = LD(c0w1, f*H_+n), b = LD(c0w1, (10+f)*H_+n);
      wP[f][n] = a - b; wQ[f][n] = b;
    }
    for (int idx = tid; idx < 160; idx += 256){
      int r = idx / 10, f = idx - (idx/10)*10;
      long row = rowBase + r; if (row >= NROW) row = NROW-1;
      xs[r][f] = g_x0[row*10 + f];
    }
    __syncthreads();
    for (int o = tid; o < 16*384; o += 256){
      int r = o / 384, n = o - (o/384)*384;
      long row = rowBase + r;
      if (row >= NROW) continue;
      float acc = 0.f;
      if (n < 192){
        #pragma unroll
        for (int f = 0; f < 10; ++f) acc += xs[r][f]*wP[f][n];
        g_P[row*192 + n] = acc;
      } else {
        int nc = n - 192;
        #pragma unroll
        for (int f = 0; f < 10; ++f) acc += xs[r][f]*wQ[f][nc];
        g_Qbf[row*192 + nc] = __float2bfloat16(acc);
      }
    }
  }
}

// ---------------- merged layer: edge-aggregate blocks + tile-gated lnpq blocks (one dispatch) ----------------
// Blocks [0,NAGG_BLKS): 2 rows each (XCD-swizzled pairs), write abf, release +2 on tile counter.
// Blocks [NAGG_BLKS, NAGG_BLKS+NT_): acquire-spin on tile counter, then m2 GEMM + deg*b2 + LN
// (+ residual) + {next-layer PQ GEMM into ping-pong Q | full head}.
template<int RES, int DOPQ, int DOHEAD>
__global__ __launch_bounds__(512) void k_layer(
    int layer, int qcur, int qnxt,
    const void* __restrict__ w1cB, long w1cO,
    const void* __restrict__ b1B, long b1O,
    const void* __restrict__ biasB, long biasO,
    const void* __restrict__ gB, long gO,
    const void* __restrict__ beB, long beO,
    int bOff, int pqOff,
    const void* __restrict__ hg, const void* __restrict__ hbe,
    const void* __restrict__ hb1, const void* __restrict__ hw2,
    const void* __restrict__ hb2, const void* __restrict__ ubase,
    const void* __restrict__ air, float* __restrict__ out,
    int M){
  int tid = threadIdx.x;
  if (blockIdx.x < NAGG_BLKS){
    // ---- edge-aggregate: pair of rows, same inner structure as standalone k_aggedge
    int o = blockIdx.x;
    int t = o & 7, s = o >> 3;     // XCD lane, pair slot
    int bk = t >> 1;
    int jp = 2*s + (t & 1);        // pair index within graph
    if (jp >= 819) return;         // 4 idle blocks
    int tile = (bk*S_ + 2*jp) >> 4;   // both rows of the pair share this tile
    int sub = tid / 192;           // 0,1 active; threads 384..511 idle
    if (sub < 2){
      int col = tid - sub*192;
      int i = 2*jp + sub;
      int row = bk*S_ + i;
      int b = bk >> 1;
      int off = g_off[b*(S_+1)+i];
      int deg = g_off[b*(S_+1)+i+1] - off;
      float w0 = LD(w1cB, w1cO+col),       w1v = LD(w1cB, w1cO+H_+col);
      float w2v = LD(w1cB, w1cO+2*H_+col), w3v = LD(w1cB, w1cO+3*H_+col);
      float base = g_P[(size_t)row*H_ + col] + LD(b1B, b1O+col);
      const int* lst = g_list + b*E_ + off;
      const bf* Q = g_Qbf + (size_t)qcur*NROW*H_ + (size_t)bk*S_*H_;
      const float* EA = g_ea + (size_t)b*E_*4;
      float acc = 0.f;
      int d = 0;
      for (; d + 8 <= deg; d += 8){
        int e[8];
        #pragma unroll
        for (int u = 0; u < 8; ++u) e[u] = lst[d+u];
        float4 a[8];
        #pragma unroll
        for (int u = 0; u < 8; ++u) a[u] = *reinterpret_cast<const float4*>(EA + (size_t)e[u]*4);
        float qv[8];
        #pragma unroll
        for (int u = 0; u < 8; ++u) qv[u] = bf2f(Q[(size_t)(e[u]>>4)*H_ + col]);
        #pragma unroll
        for (int u = 0; u < 8; ++u)
          acc += gelu_f(base + qv[u] + a[u].x*w0 + a[u].y*w1v + a[u].z*w2v + a[u].w*w3v);
      }
      for (; d + 4 <= deg; d += 4){
        int e0 = lst[d], e1 = lst[d+1], e2 = lst[d+2], e3 = lst[d+3];
        float4 a0 = *reinterpret_cast<const float4*>(EA + (size_t)e0*4);
        float4 a1 = *reinterpret_cast<const float4*>(EA + (size_t)e1*4);
        float4 a2 = *reinterpret_cast<const float4*>(EA + (size_t)e2*4);
        float4 a3 = *reinterpret_cast<const float4*>(EA + (size_t)e3*4);
        float q0 = bf2f(Q[(size_t)(e0>>4)*H_ + col]);
        float q1 = bf2f(Q[(size_t)(e1>>4)*H_ + col]);
        float q2 = bf2f(Q[(size_t)(e2>>4)*H_ + col]);
        float q3 = bf2f(Q[(size_t)(e3>>4)*H_ + col]);
        acc += gelu_f(base + q0 + a0.x*w0 + a0.y*w1v + a0.z*w2v + a0.w*w3v);
        acc += gelu_f(base + q1 + a1.x*w0 + a1.y*w1v + a1.z*w2v + a1.w*w3v);
        acc += gelu_f(base + q2 + a2.x*w0 + a2.y*w1v + a2.z*w2v + a2.w*w3v);
        acc += gelu_f(base + q3 + a3.x*w0 + a3.y*w1v + a3.z*w2v + a3.w*w3v);
      }
      for (; d < deg; ++d){
        int e = lst[d];
        float4 a = *reinterpret_cast<const float4*>(EA + (size_t)e*4);
        float qv = bf2f(Q[(size_t)(e>>4)*H_ + col]);
        acc += gelu_f(base + qv + a.x*w0 + a.y*w1v + a.z*w2v + a.w*w3v);
      }
      g_abf[(size_t)row*H_ + col] = __float2bfloat16(acc);
    }
    __syncthreads();
    if (tid == 0)
      __hip_atomic_fetch_add(&g_tdone[layer*NT_ + tile], 2,
                             __ATOMIC_RELEASE, __HIP_MEMORY_SCOPE_AGENT);
    return;
  }
  // ---- lnpq: spin until this tile's rows are aggregated
  int tileIdx = blockIdx.x - NAGG_BLKS;   // 0..409
  if (tid == 0){
    int need = (tileIdx == NT_-1) ? 8 : 16;
    while (__hip_atomic_load(&g_tdone[layer*NT_ + tileIdx],
                             __ATOMIC_ACQUIRE, __HIP_MEMORY_SCOPE_AGENT) < need)
      __builtin_amdgcn_s_sleep(16);
  }
  __syncthreads();
  const bf* A  = g_abf;
  const bf* Bp = g_w2p + bOff;
  int wv = tid >> 6, lane = tid & 63;
  int q = lane >> 4, l16 = lane & 15;
  long rowBase = (long)tileIdx * 16;
  __shared__ float tile[16][200];
  __shared__ bf    ybf[16][200];
  __shared__ float srow[16], rrow[16];
  // phase A: 12 col-tiles over 8 waves (waves 0-3 take 2, waves 4-7 take 1)
  {
    f32x4 acc[2];
    acc[0] = (f32x4){0.f,0.f,0.f,0.f};
    acc[1] = (f32x4){0.f,0.f,0.f,0.f};
    #pragma unroll
    for (int t = 0; t < 6; ++t){
      int kof = t*32 + q*8;
      long r = rowBase + l16; if (r >= M) r = M-1;
      bf16x8 af = *reinterpret_cast<const bf16x8*>(A + r*192 + kof);
      #pragma unroll
      for (int jj = 0; jj < 2; ++jj){
        int j = wv + jj*8;
        if (j < 12){
          int n = j*16 + l16;
          bf16x8 bfr = *reinterpret_cast<const bf16x8*>(Bp + (((t*4+q)*192 + n)*8));
          acc[jj] = __builtin_amdgcn_mfma_f32_16x16x32_bf16(af, bfr, acc[jj], 0,0,0);
        }
      }
    }
    float degf[4];
    #pragma unroll
    for (int r = 0; r < 4; ++r){
      int lr = q*4 + r;
      long row = rowBase + lr;
      long rowc = (row < M) ? row : (M-1);
      int bk = (int)(rowc / S_); int i = (int)(rowc - (long)bk*S_); int b = bk >> 1;
      degf[r] = (float)(g_off[b*(S_+1)+i+1] - g_off[b*(S_+1)+i]);
    }
    #pragma unroll
    for (int jj = 0; jj < 2; ++jj){
      int j = wv + jj*8;
      if (j < 12){
        int col = j*16 + l16;
        float bb = LD(biasB, biasO + col);
        #pragma unroll
        for (int r = 0; r < 4; ++r){
          int lr = q*4 + r;
          tile[lr][col] = acc[jj][r] + degf[r]*bb;
        }
      }
    }
  }
  __syncthreads();
  // LN: 2 rows per wave, 32-lane groups
  {
    int lr = wv*2 + (lane >> 5);
    int k32 = lane & 31;
    float s = 0.f, qq = 0.f;
    #pragma unroll
    for (int c6 = 0; c6 < 6; ++c6){ float x = tile[lr][k32 + c6*32]; s += x; qq += x*x; }
    #pragma unroll
    for (int o = 1; o < 32; o <<= 1){ s += __shfl_xor(s,o,64); qq += __shfl_xor(qq,o,64); }
    if (k32 == 0){
      float mu = s*(1.f/H_);
      float var = qq*(1.f/H_) - mu*mu;
      srow[lr] = mu;
      rrow[lr] = rsqrtf(fmaxf(var, 0.f) + 1e-5f);
    }
  }
  __syncthreads();
  for (int o = tid; o < 16*192; o += 512){
    int lr = o / 192, col = o - (o/192)*192;
    long row = rowBase + lr;
    long rowc = (row < M) ? row : (M-1);
    float y = (tile[lr][col] - srow[lr])*rrow[lr]*LD(gB,gO+col) + LD(beB,beO+col);
    if (RES) y += g_h[rowc*192 + col];
    if (!DOHEAD){
      if (row < M) g_h[row*192 + col] = y;
      ybf[lr][col] = __float2bfloat16(y);
    } else {
      tile[lr][col] = y;   // final h (fp32), in-place per-element
    }
  }
  if (DOPQ){
    __syncthreads();
    const bf* Bq = g_wcp + pqOff;
    bf* Qout = g_Qbf + (size_t)qnxt*NROW*H_;
    f32x4 acc2[3];
    #pragma unroll
    for (int jj = 0; jj < 3; ++jj) acc2[jj] = (f32x4){0.f,0.f,0.f,0.f};
    #pragma unroll
    for (int t = 0; t < 6; ++t){
      int kof = t*32 + q*8;
      bf16x8 af = *reinterpret_cast<const bf16x8*>(&ybf[l16][kof]);
      #pragma unroll
      for (int jj = 0; jj < 3; ++jj){
        int n = (wv*3 + jj)*16 + l16;
        bf16x8 bfr = *reinterpret_cast<const bf16x8*>(Bq + (((t*4+q)*384 + n)*8));
        acc2[jj] = __builtin_amdgcn_mfma_f32_16x16x32_bf16(af, bfr, acc2[jj], 0,0,0);
      }
    }
    #pragma unroll
    for (int jj = 0; jj < 3; ++jj){
      int col = (wv*3 + jj)*16 + l16;
      #pragma unroll
      for (int r = 0; r < 4; ++r){
        long row = rowBase + q*4 + r;
        if (row < M){
          float v = acc2[jj][r];
          if (col < 192) g_P[row*192 + col] = v;
          else           Qout[row*192 + (col-192)] = __float2bfloat16(v);
        }
      }
    }
  }
  if (DOHEAD){
    __syncthreads();
    // head LN over final h (fp32 in tile), 2 rows/wave, 32-lane groups
    {
      int lr = wv*2 + (lane >> 5);
      int k32 = lane & 31;
      float s = 0.f, qq = 0.f;
      #pragma unroll
      for (int c6 = 0; c6 < 6; ++c6){ float x = tile[lr][k32 + c6*32]; s += x; qq += x*x; }
      #pragma unroll
      for (int o = 1; o < 32; o <<= 1){ s += __shfl_xor(s,o,64); qq += __shfl_xor(qq,o,64); }
      if (k32 == 0){
        float mu = s*(1.f/H_);
        float var = qq*(1.f/H_) - mu*mu;
        srow[lr] = mu;
        rrow[lr] = rsqrtf(fmaxf(var, 0.f) + 1e-5f);
      }
    }
    __syncthreads();
    for (int o = tid; o < 16*192; o += 512){
      int lr = o / 192, col = o - (o/192)*192;
      ybf[lr][col] = __float2bfloat16((tile[lr][col] - srow[lr])*rrow[lr]*LD(hg,col) + LD(hbe,col));
    }
    __syncthreads();
    // head GEMM: hh @ hw1 (pre-packed at w2p slot 10), gelu into tile
    {
      const bf* Bh = g_w2p + 10*H_*H_;
      f32x4 hacc[2];
      hacc[0] = (f32x4){0.f,0.f,0.f,0.f};
      hacc[1] = (f32x4){0.f,0.f,0.f,0.f};
      #pragma unroll
      for (int t = 0; t < 6; ++t){
        int kof = t*32 + q*8;
        bf16x8 af = *reinterpret_cast<const bf16x8*>(&ybf[l16][kof]);
        #pragma unroll
        for (int jj = 0; jj < 2; ++jj){
          int j = wv + jj*8;
          if (j < 12){
            int n = j*16 + l16;
            bf16x8 bfr = *reinterpret_cast<const bf16x8*>(Bh + (((t*4+q)*192 + n)*8));
            hacc[jj] = __builtin_amdgcn_mfma_f32_16x16x32_bf16(af, bfr, hacc[jj], 0,0,0);
          }
        }
      }
      #pragma unroll
      for (int jj = 0; jj < 2; ++jj){
        int j = wv + jj*8;
        if (j < 12){
          int col = j*16 + l16;
          float bb = LD(hb1, col);
          #pragma unroll
          for (int r = 0; r < 4; ++r){
            int lr = q*4 + r;
            tile[lr][col] = gelu_f(hacc[jj][r] + bb);
          }
        }
      }
    }
    __syncthreads();
    // final 192x3 projection + masked scatter: 2 rows/wave, 32 lanes/row
    {
      int lr = wv*2 + (lane >> 5);
      int k32 = lane & 31;
      float p0 = 0.f, p1 = 0.f, p2 = 0.f;
      #pragma unroll
      for (int c6 = 0; c6 < 6; ++c6){
        int col = k32 + c6*32;
        float tv = tile[lr][col];
        p0 += tv*LD(hw2, col*3+0);
        p1 += tv*LD(hw2, col*3+1);
        p2 += tv*LD(hw2, col*3+2);
      }
      #pragma unroll
      for (int o = 1; o < 32; o <<= 1){
        p0 += __shfl_xor(p0,o,64);
        p1 += __shfl_xor(p1,o,64);
        p2 += __shfl_xor(p2,o,64);
      }
      if (k32 == 0){
        long row = rowBase + lr;
        if (row < M){
          int bk = (int)(row / S_), s = (int)(row - (long)bk*S_), b = bk >> 1;
          float msk = g_masksel[b*S_+s];
          int node = g_topidx[b*S_+s];
          float am = 1.f - LD(air, b*NN_+node);
          float d0 = p0 + LD(hb2,0), d1 = p1 + LD(hb2,1), d2 = p2 + LD(hb2,2);
          long oi = ((long)bk*NN_ + node)*3;
          out[oi+0] = (LD(ubase, oi+0) + d0*msk)*am;
          out[oi+1] = (LD(ubase, oi+1) + d1*msk)*am;
          out[oi+2] = (LD(ubase, oi+2) + d2*msk)*am;
        }
      }
    }
  }
}

extern "C" void kernel_launch(void* const* d_in, const int* in_sizes, int n_in,
                              void* d_out, int out_size, void* d_ws, size_t ws_size,
                              hipStream_t stream) {
  (void)in_sizes; (void)n_in; (void)d_ws; (void)ws_size; (void)out_size;
  const void* u_base = d_in[0];
  const void* pos    = d_in[1];
  const void* vel    = d_in[2];
  const void* air    = d_in[3];
  const void* c0w1   = d_in[4];
  const void* c0b1   = d_in[5];
  const void* c0w2   = d_in[6];
  const void* c0b2   = d_in[7];
  const void* c0g    = d_in[8];
  const void* c0be   = d_in[9];
  const void* cw1    = d_in[10];
  const void* cb1    = d_in[11];
  const void* cw2    = d_in[12];
  const void* cb2    = d_in[13];
  const void* cg     = d_in[14];
  const void* cbe    = d_in[15];
  const void* hg     = d_in[16];
  const void* hbe    = d_in[17];
  const void* hw1    = d_in[18];
  const void* hb1    = d_in[19];
  const void* hw2    = d_in[20];
  const void* hb2    = d_in[21];
  float* out = (float*)d_out;

  k_var<<<dim3(16, B_), 256, 0, stream>>>(vel, u_base, pos);
  k_rank<<<dim3(NN_/4, B_), 256, 0, stream>>>(pos);
  k_knngather<<<dim3(GATH_BLKS + (S_+3)/4, B_), 256, 0, stream>>>(pos, u_base, vel, air);
  k_scan<<<B_, 1024, 0, stream>>>();
  k_packall<<<PW2_BLKS + PWC_BLKS + INIT_BLKS + FILL_BLKS + PROJ_BLKS, 256, 0, stream>>>(
      c0w2, cw2, hw1, cw1, u_base, air, out, c0w1);

  const int GRID = NAGG_BLKS + NT_;   // 3690
  for (int l = 0; l < 10; ++l){
    long w1cO = (l == 0) ? 20L*H_ : ((long)(l-1)*388 + 384)*H_;
    const void* w1cB = (l == 0) ? c0w1 : cw1;
    long lOff = (l == 0) ? 0 : (long)(l-1)*H_;
    const void* b1B = (l == 0) ? c0b1 : cb1;
    const void* b2B = (l == 0) ? c0b2 : cb2;
    const void* gB  = (l == 0) ? c0g  : cg;
    const void* beB = (l == 0) ? c0be : cbe;
    int qcur = l & 1, qnxt = (l+1) & 1;
    if (l == 0)
      k_layer<0,1,0><<<GRID, 512, 0, stream>>>(l, qcur, qnxt, w1cB, w1cO, b1B, lOff,
                                               b2B, lOff, gB, lOff, beB, lOff, 0, 0,
                                               hg, hbe, hb1, hw2, hb2, u_base, air, out, NROW);
    else if (l < 9)
      k_layer<1,1,0><<<GRID, 512, 0, stream>>>(l, qcur, qnxt, w1cB, w1cO, b1B, lOff,
                                               b2B, lOff, gB, lOff, beB, lOff, l*H_*H_, l*H_*384,
                                               hg, hbe, hb1, hw2, hb2, u_base, air, out, NROW);
    else
      k_layer<1,0,1><<<GRID, 512, 0, stream>>>(l, qcur, qnxt, w1cB, w1cO, b1B, lOff,
                                               b2B, lOff, gB, lOff, beB, lOff, l*H_*H_, 0,
                                               hg, hbe, hb1, hw2, hb2, u_base, air, out, NROW);
  }
}

// Round 14
// 548.972 us; speedup vs baseline: 2.1556x; 2.1556x over previous
//
#include <hip/hip_runtime.h>
#include <hip/hip_bf16.h>
#include <math.h>

#define B_ 2
#define K_ 2
#define NN_ 4096
#define T_ 8
#define C_ 3
#define H_ 192
#define S_ 1638
#define KK_ 16
#define E_ (S_*KK_)          // 26208
#define NROW (B_*K_*S_)      // 6552
#define SHARP_ 5.0f

typedef __hip_bfloat16 bf;
typedef unsigned long long ull;
typedef __bf16 bf16x8 __attribute__((ext_vector_type(8)));
typedef float f32x4 __attribute__((ext_vector_type(4)));

__device__ int   g_isbf16;
__device__ __align__(16) float g_var[B_*NN_];
__device__ __align__(16) float g_vs1[B_*16];
__device__ __align__(16) float g_vs2[B_*16];
__device__ __align__(16) int   g_topidx[B_*S_];
__device__ __align__(16) float g_possel[B_*S_*3];
__device__ __align__(16) float g_masksel[B_*S_];
__device__ __align__(16) float g_x0[NROW*10];
__device__ __align__(16) int   g_knn[B_*E_];
__device__ __align__(16) float g_ea[B_*E_*4];
__device__ __align__(16) int   g_indeg[B_*S_];
__device__ __align__(16) int   g_cursor[B_*S_];
__device__ __align__(16) int   g_off[B_*(S_+1)];
__device__ __align__(16) int   g_list[B_*E_];
__device__ __align__(16) float g_P[(size_t)NROW*H_];
__device__ __align__(16) bf    g_Qbf[(size_t)NROW*H_];
__device__ __align__(16) float g_h[(size_t)NROW*H_];
__device__ __align__(16) bf    g_abf[(size_t)NROW*H_];
__device__ __align__(16) bf    g_w2p[(size_t)11*H_*H_];
__device__ __align__(16) bf    g_wcp[(size_t)9*H_*384];

__device__ __forceinline__ float bf2f(bf x){ return __bfloat162float(x); }
__device__ __forceinline__ float LD(const void* p, long i){
  return g_isbf16 ? __bfloat162float(((const bf*)p)[i]) : ((const float*)p)[i];
}
__device__ __forceinline__ float LDi(const void* p, long i, int isb){
  return isb ? __bfloat162float(((const bf*)p)[i]) : ((const float*)p)[i];
}
// gelu with branchless A&S 7.1.26 erf (max abs err 1.5e-7; invisible vs bf16 rounding floor)
__device__ __forceinline__ float gelu_f(float x){
  float ax = fabsf(x)*0.70710678118654752f;
  float t = 1.0f/(1.0f + 0.3275911f*ax);
  float p = t*(0.254829592f + t*(-0.284496736f + t*(1.421413741f + t*(-1.453152027f + t*1.061405429f))));
  float er = 1.0f - p*__expf(-ax*ax);
  er = copysignf(er, x);
  return 0.5f*x*(1.0f + er);
}

// ---------------- var_pp (np pairwise-8 semantics) + fused dtype-detect + state zeroing ----------------
__global__ __launch_bounds__(256) void k_var(const void* __restrict__ vel,
                                             const void* __restrict__ ub,
                                             const void* __restrict__ pos){
  __shared__ int s_bad;
  int b = blockIdx.y;
  int bx = blockIdx.x;
  int tid = threadIdx.x;
  if (tid == 0) s_bad = 0;
  __syncthreads();
  {
    const bf* pa = (const bf*)ub; const bf* pb = (const bf*)pos; const bf* pc = (const bf*)vel;
    int bad = 0;
    #pragma unroll
    for (int s = 0; s < 2; ++s){
      float va = __bfloat162float(pa[tid + s*256]);
      float vb = __bfloat162float(pb[tid + s*256]);
      float vc = __bfloat162float(pc[tid + s*256]);
      if (!(fabsf(va) <= 1000.f)) bad = 1;
      if (!(fabsf(vb) <= 1000.f)) bad = 1;
      if (!(fabsf(vc) <= 1000.f)) bad = 1;
    }
    if (bad) atomicOr(&s_bad, 1);
  }
  __syncthreads();
  int isb = (s_bad == 0) ? 1 : 0;
  if (bx == 0 && b == 0 && tid == 0) g_isbf16 = isb;
  int zi = (b*16 + bx)*256 + tid;
  if (zi < B_*S_){ g_indeg[zi] = 0; g_cursor[zi] = 0; }
  int n = bx*256 + tid;
  float v = 0.f;
  #pragma unroll
  for (int c = 0; c < 3; ++c){
    float x[8];
    #pragma unroll
    for (int t = 0; t < 8; ++t)
      x[t] = LDi(vel, ((long)(b*T_+t)*NN_ + n)*3 + c, isb);
    float m = __fadd_rn(__fadd_rn(__fadd_rn(x[0],x[1]), __fadd_rn(x[2],x[3])),
                        __fadd_rn(__fadd_rn(x[4],x[5]), __fadd_rn(x[6],x[7]))) / 8.0f;
    float d[8];
    #pragma unroll
    for (int t = 0; t < 8; ++t){ float dd = __fadd_rn(x[t], -m); d[t] = __fmul_rn(dd,dd); }
    float sv = __fadd_rn(__fadd_rn(__fadd_rn(d[0],d[1]), __fadd_rn(d[2],d[3])),
                         __fadd_rn(__fadd_rn(d[4],d[5]), __fadd_rn(d[6],d[7])));
    v = __fadd_rn(v, sv / 7.0f);
  }
  g_var[b*NN_ + n] = v;
  float s1 = v, s2 = v*v;
  #pragma unroll
  for (int o = 32; o; o >>= 1){ s1 += __shfl_xor(s1,o,64); s2 += __shfl_xor(s2,o,64); }
  __shared__ float r1[4], r2[4];
  int lane = tid & 63, wid = tid >> 6;
  if (!lane){ r1[wid]=s1; r2[wid]=s2; }
  __syncthreads();
  if (tid == 0){
    g_vs1[b*16 + bx] = r1[0]+r1[1]+r1[2]+r1[3];
    g_vs2[b*16 + bx] = r2[0]+r2[1]+r2[2]+r2[3];
  }
}

// ---------------- stable rank-based top-S: one wave per node; also emit compact possel ----------------
__global__ __launch_bounds__(256) void k_rank(const void* __restrict__ pos){
  int b = blockIdx.y;
  int i = blockIdx.x*4 + (threadIdx.x >> 6);
  int lane = threadIdx.x & 63;
  float vi = g_var[b*NN_+i];
  int rank = 0;
  for (int j = lane; j < NN_; j += 64){
    float vj = g_var[b*NN_+j];
    rank += ((vj > vi) || (vj == vi && j < i)) ? 1 : 0;
  }
  #pragma unroll
  for (int o = 32; o; o >>= 1) rank += __shfl_xor(rank, o, 64);
  if (lane == 0 && rank < S_){
    g_topidx[b*S_ + rank] = i;
    long gi = (long)(b*S_ + rank)*3;
    g_possel[gi+0] = LD(pos, ((long)b*NN_+i)*3+0);
    g_possel[gi+1] = LD(pos, ((long)b*NN_+i)*3+1);
    g_possel[gi+2] = LD(pos, ((long)b*NN_+i)*3+2);
  }
}

// ---------------- merged: gather + soft-mask (blocks 0..6) | KNN (blocks 7..) ----------------
#define GATH_BLKS 7
__global__ __launch_bounds__(256) void k_knngather(const void* __restrict__ pos,
                                                   const void* __restrict__ ub,
                                                   const void* __restrict__ vel,
                                                   const void* __restrict__ air){
  int b = blockIdx.y;
  int bx = blockIdx.x;
  if (bx < GATH_BLKS){
    int s = bx*256 + threadIdx.x;
    if (s >= S_) return;
    int gi = b*S_ + s;
    int node = g_topidx[gi];
    float px = g_possel[(long)gi*3+0];
    float py = g_possel[(long)gi*3+1];
    float pz = g_possel[(long)gi*3+2];
    float S1 = 0.f, S2 = 0.f;
    #pragma unroll
    for (int t = 0; t < 16; ++t){ S1 += g_vs1[b*16+t]; S2 += g_vs2[b*16+t]; }
    float mean = S1*(1.f/NN_);
    float sd = sqrtf(fmaxf((S2 - S1*S1*(1.f/NN_))*(1.f/(NN_-1)), 0.f));
    float vf = g_var[b*NN_+node];
    float z = (vf-mean)/(sd+1e-8f);
    float sig = 1.f/(1.f+expf(-SHARP_*z));
    g_masksel[gi] = sig*(1.f - LD(air, b*NN_+node));
    float vl0 = LD(vel, ((long)(b*T_+7)*NN_+node)*3+0);
    float vl1 = LD(vel, ((long)(b*T_+7)*NN_+node)*3+1);
    float vl2 = LD(vel, ((long)(b*T_+7)*NN_+node)*3+2);
    for (int k = 0; k < K_; ++k){
      long row = (long)(b*K_+k)*S_ + s;
      float* x = g_x0 + row*10;
      x[0]=LD(ub, ((long)(b*K_+k)*NN_+node)*3+0);
      x[1]=LD(ub, ((long)(b*K_+k)*NN_+node)*3+1);
      x[2]=LD(ub, ((long)(b*K_+k)*NN_+node)*3+2);
      x[3]=vl0; x[4]=vl1; x[5]=vl2;
      x[6]=px;  x[7]=py;  x[8]=pz;
      x[9]=vf;
    }
    return;
  }
  // ---- KNN: one wave per query node, LDS staged linearly from compact possel
  __shared__ float px[S_], py[S_], pz[S_];
  int j = (bx - GATH_BLKS)*4 + (threadIdx.x >> 6);
  int lane = threadIdx.x & 63;
  for (int t = threadIdx.x; t < S_; t += 256){
    long gi = (long)(b*S_ + t)*3;
    px[t] = g_possel[gi+0];
    py[t] = g_possel[gi+1];
    pz[t] = g_possel[gi+2];
  }
  __syncthreads();
  if (j >= S_) return;
  float xj=px[j], yj=py[j], zj=pz[j];
  float dist[KK_]; int id[KK_];
  #pragma unroll
  for (int t = 0; t < KK_; ++t){ dist[t]=3.0e38f; id[t]=0x7fffffff; }
  for (int c = lane; c < S_; c += 64){
    if (c == j) continue;
    float dx=__fadd_rn(px[c],-xj), dy=__fadd_rn(py[c],-yj), dz=__fadd_rn(pz[c],-zj);
    float d2 = __fadd_rn(__fadd_rn(__fmul_rn(dx,dx), __fmul_rn(dy,dy)), __fmul_rn(dz,dz));
    if (d2 < dist[KK_-1]){
      int p = 0;
      #pragma unroll
      for (int q = 0; q < KK_; ++q) p += (dist[q] <= d2) ? 1 : 0;
      #pragma unroll
      for (int q = KK_-1; q >= 1; --q){
        bool mv = (q > p);
        dist[q] = mv ? dist[q-1] : dist[q];
        id[q]   = mv ? id[q-1]   : id[q];
      }
      #pragma unroll
      for (int q = 0; q < KK_; ++q){ if (q == p){ dist[q] = d2; id[q] = c; } }
    }
  }
  // 16 extraction rounds: f32 min, then min-id among dist ties (== u64 (dist,id) min for dist>=0)
  unsigned selid = 0;
  #pragma unroll
  for (int t = 0; t < KK_; ++t){
    float mv = dist[0];
    #pragma unroll
    for (int o = 32; o; o >>= 1) mv = fminf(mv, __shfl_xor(mv, o, 64));
    unsigned cand = (dist[0] == mv) ? (unsigned)id[0] : 0xFFFFFFFFu;
    #pragma unroll
    for (int o = 32; o; o >>= 1){
      unsigned other = (unsigned)__shfl_xor((int)cand, o, 64);
      cand = (cand < other) ? cand : other;
    }
    if (dist[0] == mv && (unsigned)id[0] == cand){
      #pragma unroll
      for (int q = 0; q < KK_-1; ++q){ dist[q]=dist[q+1]; id[q]=id[q+1]; }
      dist[KK_-1] = 3.0e38f; id[KK_-1] = 0x7fffffff;
    }
    if (lane == t) selid = cand;
  }
  if (lane < KK_){
    int i = (int)selid;
    g_knn[(b*S_+j)*KK_ + lane] = i;
    float rx = __fadd_rn(px[i],-xj), ry = __fadd_rn(py[i],-yj), rz = __fadd_rn(pz[i],-zj);
    float dd = sqrtf(__fadd_rn(__fadd_rn(__fmul_rn(rx,rx), __fmul_rn(ry,ry)), __fmul_rn(rz,rz)));
    float* o = g_ea + ((long)b*E_ + j*KK_ + lane)*4;
    o[0]=rx; o[1]=ry; o[2]=rz; o[3]=dd;
    atomicAdd(&g_indeg[b*S_+i], 1);
  }
}

__global__ void k_scan(){
  __shared__ int sA[2048], sB[2048];
  int b = blockIdx.x, tid = threadIdx.x;   // 1024
  for (int i = tid; i < 2048; i += 1024) sA[i] = (i < S_) ? g_indeg[b*S_+i] : 0;
  __syncthreads();
  int *src = sA, *dst = sB;
  for (int d = 1; d < 2048; d <<= 1){
    for (int i = tid; i < 2048; i += 1024) dst[i] = src[i] + (i >= d ? src[i-d] : 0);
    __syncthreads();
    int* t2 = src; src = dst; dst = t2;
  }
  if (tid == 0) g_off[b*(S_+1)] = 0;
  for (int i = tid; i < S_; i += 1024) g_off[b*(S_+1)+i+1] = src[i];
}

// ---------------- fused setup: weight packing + output init + CSR fill + conv0 projection ----------------
#define PW2_BLKS 1584
#define PWC_BLKS 2592
#define INIT_BLKS 192
#define FILL_BLKS 205
#define PROJ_BLKS 410
__global__ void k_packall(const void* __restrict__ c0w2, const void* __restrict__ cw2,
                          const void* __restrict__ hw1, const void* __restrict__ cw1,
                          const void* __restrict__ ub, const void* __restrict__ air,
                          float* __restrict__ out, const void* __restrict__ c0w1){
  int blk = blockIdx.x;
  if (blk < PW2_BLKS){
    int gi = blk*256 + threadIdx.x;
    if (gi >= 11*H_*H_) return;
    int mat = gi / (H_*H_), r = gi - mat*(H_*H_);
    int k = r / H_, n = r - (r/H_)*H_;
    float v;
    if (mat == 0)      v = LD(c0w2, (long)k*H_ + n);
    else if (mat <= 9) v = LD(cw2, (long)(mat-1)*H_*H_ + (long)k*H_ + n);
    else               v = LD(hw1, (long)k*H_ + n);
    int t = k>>5, q = (k>>3)&3, jj = k&7;
    g_w2p[(size_t)mat*H_*H_ + (((t*4+q)*H_ + n)*8 + jj)] = __float2bfloat16(v);
  } else if (blk < PW2_BLKS + PWC_BLKS){
    int gi = (blk - PW2_BLKS)*256 + threadIdx.x;
    if (gi >= 9*H_*384) return;
    int l = gi / (H_*384), r = gi - l*(H_*384);
    int k = r / 384, n = r - (r/384)*384;
    long base = (long)l*388*H_;
    float v;
    if (n < H_) v = LD(cw1, base + (long)k*H_ + n) - LD(cw1, base + (long)(H_+k)*H_ + n);
    else        v = LD(cw1, base + (long)(H_+k)*H_ + (n-H_));
    int t = k>>5, q = (k>>3)&3, jj = k&7;
    g_wcp[(size_t)l*(H_*384) + (((t*4+q)*384 + n)*8 + jj)] = __float2bfloat16(v);
  } else if (blk < PW2_BLKS + PWC_BLKS + INIT_BLKS){
    int gi = (blk - PW2_BLKS - PWC_BLKS)*256 + threadIdx.x;   // 49152
    int n = (gi/3) % NN_;
    int b = gi / (K_*NN_*C_);
    float a = 1.f - LD(air, b*NN_+n);
    out[gi] = LD(ub, gi) * a;
  } else if (blk < PW2_BLKS + PWC_BLKS + INIT_BLKS + FILL_BLKS){
    int idx = (blk - PW2_BLKS - PWC_BLKS - INIT_BLKS)*256 + threadIdx.x;
    if (idx >= B_*E_) return;
    int b = idx / E_, e = idx - b*E_;
    int i = g_knn[idx];
    int slot = atomicAdd(&g_cursor[b*S_+i], 1);
    g_list[b*E_ + g_off[b*(S_+1)+i] + slot] = e;
  } else {
    // conv0 node projection (K=10), weights in LDS
    __shared__ float xs[16][10];
    __shared__ float wP[10][192];
    __shared__ float wQ[10][192];
    int tid = threadIdx.x;
    long rowBase = (long)(blk - PW2_BLKS - PWC_BLKS - INIT_BLKS - FILL_BLKS) * 16;
    for (int idx = tid; idx < 1920; idx += 256){
      int f = idx / 192, n = idx - (idx/192)*192;
      float a = LD(c0w1, f*H_+n), b = LD(c0w1, (10+f)*H_+n);
      wP[f][n] = a - b; wQ[f][n] = b;
    }
    for (int idx = tid; idx < 160; idx += 256){
      int r = idx / 10, f = idx - (idx/10)*10;
      long row = rowBase + r; if (row >= NROW) row = NROW-1;
      xs[r][f] = g_x0[row*10 + f];
    }
    __syncthreads();
    for (int o = tid; o < 16*384; o += 256){
      int r = o / 384, n = o - (o/384)*384;
      long row = rowBase + r;
      if (row >= NROW) continue;
      float acc = 0.f;
      if (n < 192){
        #pragma unroll
        for (int f = 0; f < 10; ++f) acc += xs[r][f]*wP[f][n];
        g_P[row*192 + n] = acc;
      } else {
        int nc = n - 192;
        #pragma unroll
        for (int f = 0; f < 10; ++f) acc += xs[r][f]*wQ[f][nc];
        g_Qbf[row*192 + nc] = __float2bfloat16(acc);
      }
    }
  }
}

// ---------------- fused edge-compute + CSR aggregate, XCD-swizzled rows, unroll x8 ----------------
__global__ __launch_bounds__(192) void k_aggedge(const void* __restrict__ w1cB, long w1cO,
                                                 const void* __restrict__ b1B, long b1O){
  int o = blockIdx.x;            // 6552
  int t = o & 7, s = o >> 3;     // s in 0..818
  int bk = t >> 1;               // 0..3
  int row = bk*S_ + 2*s + (t & 1);   // bijective over NROW
  int col = threadIdx.x;         // 192
  int i = row - bk*S_, b = bk >> 1;
  int off = g_off[b*(S_+1)+i];
  int deg = g_off[b*(S_+1)+i+1] - off;
  float w0 = LD(w1cB, w1cO+col),       w1v = LD(w1cB, w1cO+H_+col);
  float w2v = LD(w1cB, w1cO+2*H_+col), w3v = LD(w1cB, w1cO+3*H_+col);
  float base = g_P[(size_t)row*H_ + col] + LD(b1B, b1O+col);
  const int* lst = g_list + b*E_ + off;
  const bf* Q = g_Qbf + (size_t)bk*S_*H_;
  const float* EA = g_ea + (size_t)b*E_*4;
  float acc = 0.f;
  int d = 0;
  for (; d + 8 <= deg; d += 8){
    int e[8];
    #pragma unroll
    for (int u = 0; u < 8; ++u) e[u] = lst[d+u];
    float4 a[8];
    #pragma unroll
    for (int u = 0; u < 8; ++u) a[u] = *reinterpret_cast<const float4*>(EA + (size_t)e[u]*4);
    float qv[8];
    #pragma unroll
    for (int u = 0; u < 8; ++u) qv[u] = bf2f(Q[(size_t)(e[u]>>4)*H_ + col]);
    #pragma unroll
    for (int u = 0; u < 8; ++u)
      acc += gelu_f(base + qv[u] + a[u].x*w0 + a[u].y*w1v + a[u].z*w2v + a[u].w*w3v);
  }
  for (; d + 4 <= deg; d += 4){
    int e0 = lst[d], e1 = lst[d+1], e2 = lst[d+2], e3 = lst[d+3];
    float4 a0 = *reinterpret_cast<const float4*>(EA + (size_t)e0*4);
    float4 a1 = *reinterpret_cast<const float4*>(EA + (size_t)e1*4);
    float4 a2 = *reinterpret_cast<const float4*>(EA + (size_t)e2*4);
    float4 a3 = *reinterpret_cast<const float4*>(EA + (size_t)e3*4);
    float q0 = bf2f(Q[(size_t)(e0>>4)*H_ + col]);
    float q1 = bf2f(Q[(size_t)(e1>>4)*H_ + col]);
    float q2 = bf2f(Q[(size_t)(e2>>4)*H_ + col]);
    float q3 = bf2f(Q[(size_t)(e3>>4)*H_ + col]);
    acc += gelu_f(base + q0 + a0.x*w0 + a0.y*w1v + a0.z*w2v + a0.w*w3v);
    acc += gelu_f(base + q1 + a1.x*w0 + a1.y*w1v + a1.z*w2v + a1.w*w3v);
    acc += gelu_f(base + q2 + a2.x*w0 + a2.y*w1v + a2.z*w2v + a2.w*w3v);
    acc += gelu_f(base + q3 + a3.x*w0 + a3.y*w1v + a3.z*w2v + a3.w*w3v);
  }
  for (; d < deg; ++d){
    int e = lst[d];
    float4 a = *reinterpret_cast<const float4*>(EA + (size_t)e*4);
    float qv = bf2f(Q[(size_t)(e>>4)*H_ + col]);
    acc += gelu_f(base + qv + a.x*w0 + a.y*w1v + a.z*w2v + a.w*w3v);
  }
  g_abf[(size_t)row*H_ + col] = __float2bfloat16(acc);
}

// ---------------- fused: m2 GEMM + deg*b2 + LN + residual + {next-layer PQ GEMM | full head} ----------------
template<int RES, int DOPQ, int DOHEAD>
__global__ __launch_bounds__(512) void k_lnpq(const void* __restrict__ biasB, long biasO,
                                              const void* __restrict__ gB, long gO,
                                              const void* __restrict__ beB, long beO,
                                              int bOff, int pqOff,
                                              const void* __restrict__ hg, const void* __restrict__ hbe,
                                              const void* __restrict__ hb1, const void* __restrict__ hw2,
                                              const void* __restrict__ hb2, const void* __restrict__ ubase,
                                              const void* __restrict__ air, float* __restrict__ out,
                                              int M){
  const bf* A  = g_abf;
  const bf* Bp = g_w2p + bOff;
  int tid = threadIdx.x;
  int wv = tid >> 6, lane = tid & 63;
  int q = lane >> 4, l16 = lane & 15;
  long rowBase = (long)blockIdx.x * 16;
  __shared__ float tile[16][200];
  __shared__ bf    ybf[16][200];
  __shared__ float srow[16], rrow[16];
  // phase A: 12 col-tiles over 8 waves (waves 0-3 take 2, waves 4-7 take 1)
  {
    f32x4 acc[2];
    acc[0] = (f32x4){0.f,0.f,0.f,0.f};
    acc[1] = (f32x4){0.f,0.f,0.f,0.f};
    #pragma unroll
    for (int t = 0; t < 6; ++t){
      int kof = t*32 + q*8;
      long r = rowBase + l16; if (r >= M) r = M-1;
      bf16x8 af = *reinterpret_cast<const bf16x8*>(A + r*192 + kof);
      #pragma unroll
      for (int jj = 0; jj < 2; ++jj){
        int j = wv + jj*8;
        if (j < 12){
          int n = j*16 + l16;
          bf16x8 bfr = *reinterpret_cast<const bf16x8*>(Bp + (((t*4+q)*192 + n)*8));
          acc[jj] = __builtin_amdgcn_mfma_f32_16x16x32_bf16(af, bfr, acc[jj], 0,0,0);
        }
      }
    }
    float degf[4];
    #pragma unroll
    for (int r = 0; r < 4; ++r){
      int lr = q*4 + r;
      long row = rowBase + lr;
      long rowc = (row < M) ? row : (M-1);
      int bk = (int)(rowc / S_); int i = (int)(rowc - (long)bk*S_); int b = bk >> 1;
      degf[r] = (float)(g_off[b*(S_+1)+i+1] - g_off[b*(S_+1)+i]);
    }
    #pragma unroll
    for (int jj = 0; jj < 2; ++jj){
      int j = wv + jj*8;
      if (j < 12){
        int col = j*16 + l16;
        float bb = LD(biasB, biasO + col);
        #pragma unroll
        for (int r = 0; r < 4; ++r){
          int lr = q*4 + r;
          tile[lr][col] = acc[jj][r] + degf[r]*bb;
        }
      }
    }
  }
  __syncthreads();
  // LN: 2 rows per wave, 32-lane groups
  {
    int lr = wv*2 + (lane >> 5);
    int k32 = lane & 31;
    float s = 0.f, qq = 0.f;
    #pragma unroll
    for (int c6 = 0; c6 < 6; ++c6){ float x = tile[lr][k32 + c6*32]; s += x; qq += x*x; }
    #pragma unroll
    for (int o = 1; o < 32; o <<= 1){ s += __shfl_xor(s,o,64); qq += __shfl_xor(qq,o,64); }
    if (k32 == 0){
      float mu = s*(1.f/H_);
      float var = qq*(1.f/H_) - mu*mu;
      srow[lr] = mu;
      rrow[lr] = rsqrtf(fmaxf(var, 0.f) + 1e-5f);
    }
  }
  __syncthreads();
  for (int o = tid; o < 16*192; o += 512){
    int lr = o / 192, col = o - (o/192)*192;
    long row = rowBase + lr;
    long rowc = (row < M) ? row : (M-1);
    float y = (tile[lr][col] - srow[lr])*rrow[lr]*LD(gB,gO+col) + LD(beB,beO+col);
    if (RES) y += g_h[rowc*192 + col];
    if (!DOHEAD){
      if (row < M) g_h[row*192 + col] = y;
      ybf[lr][col] = __float2bfloat16(y);
    } else {
      tile[lr][col] = y;   // final h (fp32), in-place per-element
    }
  }
  if (DOPQ){
    __syncthreads();
    const bf* Bq = g_wcp + pqOff;
    f32x4 acc2[3];
    #pragma unroll
    for (int jj = 0; jj < 3; ++jj) acc2[jj] = (f32x4){0.f,0.f,0.f,0.f};
    #pragma unroll
    for (int t = 0; t < 6; ++t){
      int kof = t*32 + q*8;
      bf16x8 af = *reinterpret_cast<const bf16x8*>(&ybf[l16][kof]);
      #pragma unroll
      for (int jj = 0; jj < 3; ++jj){
        int n = (wv*3 + jj)*16 + l16;
        bf16x8 bfr = *reinterpret_cast<const bf16x8*>(Bq + (((t*4+q)*384 + n)*8));
        acc2[jj] = __builtin_amdgcn_mfma_f32_16x16x32_bf16(af, bfr, acc2[jj], 0,0,0);
      }
    }
    #pragma unroll
    for (int jj = 0; jj < 3; ++jj){
      int col = (wv*3 + jj)*16 + l16;
      #pragma unroll
      for (int r = 0; r < 4; ++r){
        long row = rowBase + q*4 + r;
        if (row < M){
          float v = acc2[jj][r];
          if (col < 192) g_P[row*192 + col] = v;
          else           g_Qbf[row*192 + (col-192)] = __float2bfloat16(v);
        }
      }
    }
  }
  if (DOHEAD){
    __syncthreads();
    // head LN over final h (fp32 in tile), 2 rows/wave, 32-lane groups
    {
      int lr = wv*2 + (lane >> 5);
      int k32 = lane & 31;
      float s = 0.f, qq = 0.f;
      #pragma unroll
      for (int c6 = 0; c6 < 6; ++c6){ float x = tile[lr][k32 + c6*32]; s += x; qq += x*x; }
      #pragma unroll
      for (int o = 1; o < 32; o <<= 1){ s += __shfl_xor(s,o,64); qq += __shfl_xor(qq,o,64); }
      if (k32 == 0){
        float mu = s*(1.f/H_);
        float var = qq*(1.f/H_) - mu*mu;
        srow[lr] = mu;
        rrow[lr] = rsqrtf(fmaxf(var, 0.f) + 1e-5f);
      }
    }
    __syncthreads();
    for (int o = tid; o < 16*192; o += 512){
      int lr = o / 192, col = o - (o/192)*192;
      ybf[lr][col] = __float2bfloat16((tile[lr][col] - srow[lr])*rrow[lr]*LD(hg,col) + LD(hbe,col));
    }
    __syncthreads();
    // head GEMM: hh @ hw1 (pre-packed at w2p slot 10), gelu into tile
    {
      const bf* Bh = g_w2p + 10*H_*H_;
      f32x4 hacc[2];
      hacc[0] = (f32x4){0.f,0.f,0.f,0.f};
      hacc[1] = (f32x4){0.f,0.f,0.f,0.f};
      #pragma unroll
      for (int t = 0; t < 6; ++t){
        int kof = t*32 + q*8;
        bf16x8 af = *reinterpret_cast<const bf16x8*>(&ybf[l16][kof]);
        #pragma unroll
        for (int jj = 0; jj < 2; ++jj){
          int j = wv + jj*8;
          if (j < 12){
            int n = j*16 + l16;
            bf16x8 bfr = *reinterpret_cast<const bf16x8*>(Bh + (((t*4+q)*192 + n)*8));
            hacc[jj] = __builtin_amdgcn_mfma_f32_16x16x32_bf16(af, bfr, hacc[jj], 0,0,0);
          }
        }
      }
      #pragma unroll
      for (int jj = 0; jj < 2; ++jj){
        int j = wv + jj*8;
        if (j < 12){
          int col = j*16 + l16;
          float bb = LD(hb1, col);
          #pragma unroll
          for (int r = 0; r < 4; ++r){
            int lr = q*4 + r;
            tile[lr][col] = gelu_f(hacc[jj][r] + bb);
          }
        }
      }
    }
    __syncthreads();
    // final 192x3 projection + masked scatter: 2 rows/wave, 32 lanes/row
    {
      int lr = wv*2 + (lane >> 5);
      int k32 = lane & 31;
      float p0 = 0.f, p1 = 0.f, p2 = 0.f;
      #pragma unroll
      for (int c6 = 0; c6 < 6; ++c6){
        int col = k32 + c6*32;
        float tv = tile[lr][col];
        p0 += tv*LD(hw2, col*3+0);
        p1 += tv*LD(hw2, col*3+1);
        p2 += tv*LD(hw2, col*3+2);
      }
      #pragma unroll
      for (int o = 1; o < 32; o <<= 1){
        p0 += __shfl_xor(p0,o,64);
        p1 += __shfl_xor(p1,o,64);
        p2 += __shfl_xor(p2,o,64);
      }
      if (k32 == 0){
        long row = rowBase + lr;
        if (row < M){
          int bk = (int)(row / S_), s = (int)(row - (long)bk*S_), b = bk >> 1;
          float msk = g_masksel[b*S_+s];
          int node = g_topidx[b*S_+s];
          float am = 1.f - LD(air, b*NN_+node);
          float d0 = p0 + LD(hb2,0), d1 = p1 + LD(hb2,1), d2 = p2 + LD(hb2,2);
          long oi = ((long)bk*NN_ + node)*3;
          out[oi+0] = (LD(ubase, oi+0) + d0*msk)*am;
          out[oi+1] = (LD(ubase, oi+1) + d1*msk)*am;
          out[oi+2] = (LD(ubase, oi+2) + d2*msk)*am;
        }
      }
    }
  }
}

extern "C" void kernel_launch(void* const* d_in, const int* in_sizes, int n_in,
                              void* d_out, int out_size, void* d_ws, size_t ws_size,
                              hipStream_t stream) {
  (void)in_sizes; (void)n_in; (void)d_ws; (void)ws_size; (void)out_size;
  const void* u_base = d_in[0];
  const void* pos    = d_in[1];
  const void* vel    = d_in[2];
  const void* air    = d_in[3];
  const void* c0w1   = d_in[4];
  const void* c0b1   = d_in[5];
  const void* c0w2   = d_in[6];
  const void* c0b2   = d_in[7];
  const void* c0g    = d_in[8];
  const void* c0be   = d_in[9];
  const void* cw1    = d_in[10];
  const void* cb1    = d_in[11];
  const void* cw2    = d_in[12];
  const void* cb2    = d_in[13];
  const void* cg     = d_in[14];
  const void* cbe    = d_in[15];
  const void* hg     = d_in[16];
  const void* hbe    = d_in[17];
  const void* hw1    = d_in[18];
  const void* hb1    = d_in[19];
  const void* hw2    = d_in[20];
  const void* hb2    = d_in[21];
  float* out = (float*)d_out;

  k_var<<<dim3(16, B_), 256, 0, stream>>>(vel, u_base, pos);
  k_rank<<<dim3(NN_/4, B_), 256, 0, stream>>>(pos);
  k_knngather<<<dim3(GATH_BLKS + (S_+3)/4, B_), 256, 0, stream>>>(pos, u_base, vel, air);
  k_scan<<<B_, 1024, 0, stream>>>();
  k_packall<<<PW2_BLKS + PWC_BLKS + INIT_BLKS + FILL_BLKS + PROJ_BLKS, 256, 0, stream>>>(
      c0w2, cw2, hw1, cw1, u_base, air, out, c0w1);

  const int GN16 = (NROW + 15) / 16;   // 410
  for (int l = 0; l < 10; ++l){
    long w1cO = (l == 0) ? 20L*H_ : ((long)(l-1)*388 + 384)*H_;
    const void* w1cB = (l == 0) ? c0w1 : cw1;
    long lOff = (l == 0) ? 0 : (long)(l-1)*H_;
    const void* b1B = (l == 0) ? c0b1 : cb1;
    k_aggedge<<<NROW, 192, 0, stream>>>(w1cB, w1cO, b1B, lOff);

    const void* b2B = (l == 0) ? c0b2 : cb2;
    const void* gB  = (l == 0) ? c0g  : cg;
    const void* beB = (l == 0) ? c0be : cbe;
    if (l == 0)
      k_lnpq<0,1,0><<<GN16, 512, 0, stream>>>(b2B, lOff, gB, lOff, beB, lOff, 0,        0,
                                              hg, hbe, hb1, hw2, hb2, u_base, air, out, NROW);
    else if (l < 9)
      k_lnpq<1,1,0><<<GN16, 512, 0, stream>>>(b2B, lOff, gB, lOff, beB, lOff, l*H_*H_, l*H_*384,
                                              hg, hbe, hb1, hw2, hb2, u_base, air, out, NROW);
    else
      k_lnpq<1,0,1><<<GN16, 512, 0, stream>>>(b2B, lOff, gB, lOff, beB, lOff, l*H_*H_, 0,
                                              hg, hbe, hb1, hw2, hb2, u_base, air, out, NROW);
  }
}

// Round 15
// 544.460 us; speedup vs baseline: 2.1735x; 1.0083x over previous
//
#include <hip/hip_runtime.h>
#include <hip/hip_bf16.h>
#include <math.h>

#define B_ 2
#define K_ 2
#define NN_ 4096
#define T_ 8
#define C_ 3
#define H_ 192
#define S_ 1638
#define KK_ 16
#define E_ (S_*KK_)          // 26208
#define NROW (B_*K_*S_)      // 6552
#define SHARP_ 5.0f

typedef __hip_bfloat16 bf;
typedef unsigned long long ull;
typedef __bf16 bf16x8 __attribute__((ext_vector_type(8)));
typedef float f32x4 __attribute__((ext_vector_type(4)));

__device__ int   g_isbf16;
__device__ __align__(16) float g_var[B_*NN_];
__device__ __align__(16) float g_vs1[B_*16];
__device__ __align__(16) float g_vs2[B_*16];
__device__ __align__(16) int   g_topidx[B_*S_];
__device__ __align__(16) float g_possel[B_*S_*3];
__device__ __align__(16) float g_masksel[B_*S_];
__device__ __align__(16) float g_x0[NROW*10];
__device__ __align__(16) int   g_knn[B_*E_];
__device__ __align__(16) float g_ea[B_*E_*4];
__device__ __align__(16) int   g_indeg[B_*S_];
__device__ __align__(16) int   g_cursor[B_*S_];
__device__ __align__(16) int   g_off[B_*(S_+1)];
__device__ __align__(16) int   g_list[B_*E_];
__device__ __align__(16) float g_P[(size_t)NROW*H_];
__device__ __align__(16) bf    g_Qbf[(size_t)NROW*H_];
__device__ __align__(16) float g_h[(size_t)NROW*H_];
__device__ __align__(16) bf    g_abf[(size_t)NROW*H_];
__device__ __align__(16) bf    g_w2p[(size_t)11*H_*H_];
__device__ __align__(16) bf    g_wcp[(size_t)9*H_*384];

__device__ __forceinline__ float bf2f(bf x){ return __bfloat162float(x); }
__device__ __forceinline__ float LD(const void* p, long i){
  return g_isbf16 ? __bfloat162float(((const bf*)p)[i]) : ((const float*)p)[i];
}
__device__ __forceinline__ float LDi(const void* p, long i, int isb){
  return isb ? __bfloat162float(((const bf*)p)[i]) : ((const float*)p)[i];
}
// gelu with branchless A&S 7.1.26 erf (max abs err 1.5e-7; invisible vs bf16 rounding floor)
__device__ __forceinline__ float gelu_f(float x){
  float ax = fabsf(x)*0.70710678118654752f;
  float t = 1.0f/(1.0f + 0.3275911f*ax);
  float p = t*(0.254829592f + t*(-0.284496736f + t*(1.421413741f + t*(-1.453152027f + t*1.061405429f))));
  float er = 1.0f - p*__expf(-ax*ax);
  er = copysignf(er, x);
  return 0.5f*x*(1.0f + er);
}
__device__ __forceinline__ ull shfl_xor_u64(ull v, int m){
  unsigned lo = (unsigned)v, hi = (unsigned)(v >> 32);
  lo = __shfl_xor(lo, m, 64); hi = __shfl_xor(hi, m, 64);
  return ((ull)hi << 32) | lo;
}

// ---------------- var_pp (np pairwise-8 semantics) + fused dtype-detect + state zeroing ----------------
__global__ __launch_bounds__(256) void k_var(const void* __restrict__ vel,
                                             const void* __restrict__ ub,
                                             const void* __restrict__ pos){
  __shared__ int s_bad;
  int b = blockIdx.y;
  int bx = blockIdx.x;
  int tid = threadIdx.x;
  if (tid == 0) s_bad = 0;
  __syncthreads();
  {
    const bf* pa = (const bf*)ub; const bf* pb = (const bf*)pos; const bf* pc = (const bf*)vel;
    int bad = 0;
    #pragma unroll
    for (int s = 0; s < 2; ++s){
      float va = __bfloat162float(pa[tid + s*256]);
      float vb = __bfloat162float(pb[tid + s*256]);
      float vc = __bfloat162float(pc[tid + s*256]);
      if (!(fabsf(va) <= 1000.f)) bad = 1;
      if (!(fabsf(vb) <= 1000.f)) bad = 1;
      if (!(fabsf(vc) <= 1000.f)) bad = 1;
    }
    if (bad) atomicOr(&s_bad, 1);
  }
  __syncthreads();
  int isb = (s_bad == 0) ? 1 : 0;
  if (bx == 0 && b == 0 && tid == 0) g_isbf16 = isb;
  int zi = (b*16 + bx)*256 + tid;
  if (zi < B_*S_){ g_indeg[zi] = 0; g_cursor[zi] = 0; }
  int n = bx*256 + tid;
  float v = 0.f;
  #pragma unroll
  for (int c = 0; c < 3; ++c){
    float x[8];
    #pragma unroll
    for (int t = 0; t < 8; ++t)
      x[t] = LDi(vel, ((long)(b*T_+t)*NN_ + n)*3 + c, isb);
    float m = __fadd_rn(__fadd_rn(__fadd_rn(x[0],x[1]), __fadd_rn(x[2],x[3])),
                        __fadd_rn(__fadd_rn(x[4],x[5]), __fadd_rn(x[6],x[7]))) / 8.0f;
    float d[8];
    #pragma unroll
    for (int t = 0; t < 8; ++t){ float dd = __fadd_rn(x[t], -m); d[t] = __fmul_rn(dd,dd); }
    float sv = __fadd_rn(__fadd_rn(__fadd_rn(d[0],d[1]), __fadd_rn(d[2],d[3])),
                         __fadd_rn(__fadd_rn(d[4],d[5]), __fadd_rn(d[6],d[7])));
    v = __fadd_rn(v, sv / 7.0f);
  }
  g_var[b*NN_ + n] = v;
  float s1 = v, s2 = v*v;
  #pragma unroll
  for (int o = 32; o; o >>= 1){ s1 += __shfl_xor(s1,o,64); s2 += __shfl_xor(s2,o,64); }
  __shared__ float r1[4], r2[4];
  int lane = tid & 63, wid = tid >> 6;
  if (!lane){ r1[wid]=s1; r2[wid]=s2; }
  __syncthreads();
  if (tid == 0){
    g_vs1[b*16 + bx] = r1[0]+r1[1]+r1[2]+r1[3];
    g_vs2[b*16 + bx] = r2[0]+r2[1]+r2[2]+r2[3];
  }
}

// ---------------- stable rank-based top-S: one wave per node; also emit compact possel ----------------
__global__ __launch_bounds__(256) void k_rank(const void* __restrict__ pos){
  int b = blockIdx.y;
  int i = blockIdx.x*4 + (threadIdx.x >> 6);
  int lane = threadIdx.x & 63;
  float vi = g_var[b*NN_+i];
  int rank = 0;
  for (int j = lane; j < NN_; j += 64){
    float vj = g_var[b*NN_+j];
    rank += ((vj > vi) || (vj == vi && j < i)) ? 1 : 0;
  }
  #pragma unroll
  for (int o = 32; o; o >>= 1) rank += __shfl_xor(rank, o, 64);
  if (lane == 0 && rank < S_){
    g_topidx[b*S_ + rank] = i;
    long gi = (long)(b*S_ + rank)*3;
    g_possel[gi+0] = LD(pos, ((long)b*NN_+i)*3+0);
    g_possel[gi+1] = LD(pos, ((long)b*NN_+i)*3+1);
    g_possel[gi+2] = LD(pos, ((long)b*NN_+i)*3+2);
  }
}

// ---------------- merged: gather + soft-mask (blocks 0..6) | KNN (blocks 7..) ----------------
#define GATH_BLKS 7
__global__ __launch_bounds__(256) void k_knngather(const void* __restrict__ pos,
                                                   const void* __restrict__ ub,
                                                   const void* __restrict__ vel,
                                                   const void* __restrict__ air){
  int b = blockIdx.y;
  int bx = blockIdx.x;
  if (bx < GATH_BLKS){
    int s = bx*256 + threadIdx.x;
    if (s >= S_) return;
    int gi = b*S_ + s;
    int node = g_topidx[gi];
    float px = g_possel[(long)gi*3+0];
    float py = g_possel[(long)gi*3+1];
    float pz = g_possel[(long)gi*3+2];
    float S1 = 0.f, S2 = 0.f;
    #pragma unroll
    for (int t = 0; t < 16; ++t){ S1 += g_vs1[b*16+t]; S2 += g_vs2[b*16+t]; }
    float mean = S1*(1.f/NN_);
    float sd = sqrtf(fmaxf((S2 - S1*S1*(1.f/NN_))*(1.f/(NN_-1)), 0.f));
    float vf = g_var[b*NN_+node];
    float z = (vf-mean)/(sd+1e-8f);
    float sig = 1.f/(1.f+expf(-SHARP_*z));
    g_masksel[gi] = sig*(1.f - LD(air, b*NN_+node));
    float vl0 = LD(vel, ((long)(b*T_+7)*NN_+node)*3+0);
    float vl1 = LD(vel, ((long)(b*T_+7)*NN_+node)*3+1);
    float vl2 = LD(vel, ((long)(b*T_+7)*NN_+node)*3+2);
    for (int k = 0; k < K_; ++k){
      long row = (long)(b*K_+k)*S_ + s;
      float* x = g_x0 + row*10;
      x[0]=LD(ub, ((long)(b*K_+k)*NN_+node)*3+0);
      x[1]=LD(ub, ((long)(b*K_+k)*NN_+node)*3+1);
      x[2]=LD(ub, ((long)(b*K_+k)*NN_+node)*3+2);
      x[3]=vl0; x[4]=vl1; x[5]=vl2;
      x[6]=px;  x[7]=py;  x[8]=pz;
      x[9]=vf;
    }
    return;
  }
  // ---- KNN: one wave per query node, LDS staged linearly from compact possel
  __shared__ float px[S_], py[S_], pz[S_];
  int j = (bx - GATH_BLKS)*4 + (threadIdx.x >> 6);
  int lane = threadIdx.x & 63;
  for (int t = threadIdx.x; t < S_; t += 256){
    long gi = (long)(b*S_ + t)*3;
    px[t] = g_possel[gi+0];
    py[t] = g_possel[gi+1];
    pz[t] = g_possel[gi+2];
  }
  __syncthreads();
  if (j >= S_) return;
  float xj=px[j], yj=py[j], zj=pz[j];
  float dist[KK_]; int id[KK_];
  #pragma unroll
  for (int t = 0; t < KK_; ++t){ dist[t]=3.0e38f; id[t]=0x7fffffff; }
  for (int c = lane; c < S_; c += 64){
    if (c == j) continue;
    float dx=__fadd_rn(px[c],-xj), dy=__fadd_rn(py[c],-yj), dz=__fadd_rn(pz[c],-zj);
    float d2 = __fadd_rn(__fadd_rn(__fmul_rn(dx,dx), __fmul_rn(dy,dy)), __fmul_rn(dz,dz));
    if (d2 < dist[KK_-1]){
      int p = 0;
      #pragma unroll
      for (int q = 0; q < KK_; ++q) p += (dist[q] <= d2) ? 1 : 0;
      #pragma unroll
      for (int q = KK_-1; q >= 1; --q){
        bool mv = (q > p);
        dist[q] = mv ? dist[q-1] : dist[q];
        id[q]   = mv ? id[q-1]   : id[q];
      }
      #pragma unroll
      for (int q = 0; q < KK_; ++q){ if (q == p){ dist[q] = d2; id[q] = c; } }
    }
  }
  ull mykey = 0;
  #pragma unroll
  for (int t = 0; t < KK_; ++t){
    ull k = (((ull)__float_as_uint(dist[0])) << 32) | (unsigned)id[0];
    ull m = k;
    #pragma unroll
    for (int o = 32; o; o >>= 1){ ull other = shfl_xor_u64(m, o); m = (other < m) ? other : m; }
    if (k == m){
      #pragma unroll
      for (int q = 0; q < KK_-1; ++q){ dist[q]=dist[q+1]; id[q]=id[q+1]; }
      dist[KK_-1] = 3.0e38f; id[KK_-1] = 0x7fffffff;
    }
    if (lane == t) mykey = m;
  }
  if (lane < KK_){
    int i = (int)(mykey & 0xffffffffu);
    g_knn[(b*S_+j)*KK_ + lane] = i;
    float rx = __fadd_rn(px[i],-xj), ry = __fadd_rn(py[i],-yj), rz = __fadd_rn(pz[i],-zj);
    float dd = sqrtf(__fadd_rn(__fadd_rn(__fmul_rn(rx,rx), __fmul_rn(ry,ry)), __fmul_rn(rz,rz)));
    float* o = g_ea + ((long)b*E_ + j*KK_ + lane)*4;
    o[0]=rx; o[1]=ry; o[2]=rz; o[3]=dd;
    atomicAdd(&g_indeg[b*S_+i], 1);
  }
}

__global__ void k_scan(){
  __shared__ int sA[2048], sB[2048];
  int b = blockIdx.x, tid = threadIdx.x;   // 1024
  for (int i = tid; i < 2048; i += 1024) sA[i] = (i < S_) ? g_indeg[b*S_+i] : 0;
  __syncthreads();
  int *src = sA, *dst = sB;
  for (int d = 1; d < 2048; d <<= 1){
    for (int i = tid; i < 2048; i += 1024) dst[i] = src[i] + (i >= d ? src[i-d] : 0);
    __syncthreads();
    int* t2 = src; src = dst; dst = t2;
  }
  if (tid == 0) g_off[b*(S_+1)] = 0;
  for (int i = tid; i < S_; i += 1024) g_off[b*(S_+1)+i+1] = src[i];
}

// ---------------- fused setup: weight packing + output init + CSR fill + conv0 projection ----------------
#define PW2_BLKS 1584
#define PWC_BLKS 2592
#define INIT_BLKS 192
#define FILL_BLKS 205
#define PROJ_BLKS 410
__global__ void k_packall(const void* __restrict__ c0w2, const void* __restrict__ cw2,
                          const void* __restrict__ hw1, const void* __restrict__ cw1,
                          const void* __restrict__ ub, const void* __restrict__ air,
                          float* __restrict__ out, const void* __restrict__ c0w1){
  int blk = blockIdx.x;
  if (blk < PW2_BLKS){
    int gi = blk*256 + threadIdx.x;
    if (gi >= 11*H_*H_) return;
    int mat = gi / (H_*H_), r = gi - mat*(H_*H_);
    int k = r / H_, n = r - (r/H_)*H_;
    float v;
    if (mat == 0)      v = LD(c0w2, (long)k*H_ + n);
    else if (mat <= 9) v = LD(cw2, (long)(mat-1)*H_*H_ + (long)k*H_ + n);
    else               v = LD(hw1, (long)k*H_ + n);
    int t = k>>5, q = (k>>3)&3, jj = k&7;
    g_w2p[(size_t)mat*H_*H_ + (((t*4+q)*H_ + n)*8 + jj)] = __float2bfloat16(v);
  } else if (blk < PW2_BLKS + PWC_BLKS){
    int gi = (blk - PW2_BLKS)*256 + threadIdx.x;
    if (gi >= 9*H_*384) return;
    int l = gi / (H_*384), r = gi - l*(H_*384);
    int k = r / 384, n = r - (r/384)*384;
    long base = (long)l*388*H_;
    float v;
    if (n < H_) v = LD(cw1, base + (long)k*H_ + n) - LD(cw1, base + (long)(H_+k)*H_ + n);
    else        v = LD(cw1, base + (long)(H_+k)*H_ + (n-H_));
    int t = k>>5, q = (k>>3)&3, jj = k&7;
    g_wcp[(size_t)l*(H_*384) + (((t*4+q)*384 + n)*8 + jj)] = __float2bfloat16(v);
  } else if (blk < PW2_BLKS + PWC_BLKS + INIT_BLKS){
    int gi = (blk - PW2_BLKS - PWC_BLKS)*256 + threadIdx.x;   // 49152
    int n = (gi/3) % NN_;
    int b = gi / (K_*NN_*C_);
    float a = 1.f - LD(air, b*NN_+n);
    out[gi] = LD(ub, gi) * a;
  } else if (blk < PW2_BLKS + PWC_BLKS + INIT_BLKS + FILL_BLKS){
    int idx = (blk - PW2_BLKS - PWC_BLKS - INIT_BLKS)*256 + threadIdx.x;
    if (idx >= B_*E_) return;
    int b = idx / E_, e = idx - b*E_;
    int i = g_knn[idx];
    int slot = atomicAdd(&g_cursor[b*S_+i], 1);
    g_list[b*E_ + g_off[b*(S_+1)+i] + slot] = e;
  } else {
    // conv0 node projection (K=10), weights in LDS
    __shared__ float xs[16][10];
    __shared__ float wP[10][192];
    __shared__ float wQ[10][192];
    int tid = threadIdx.x;
    long rowBase = (long)(blk - PW2_BLKS - PWC_BLKS - INIT_BLKS - FILL_BLKS) * 16;
    for (int idx = tid; idx < 1920; idx += 256){
      int f = idx / 192, n = idx - (idx/192)*192;
      float a = LD(c0w1, f*H_+n), b = LD(c0w1, (10+f)*H_+n);
      wP[f][n] = a - b; wQ[f][n] = b;
    }
    for (int idx = tid; idx < 160; idx += 256){
      int r = idx / 10, f = idx - (idx/10)*10;
      long row = rowBase + r; if (row >= NROW) row = NROW-1;
      xs[r][f] = g_x0[row*10 + f];
    }
    __syncthreads();
    for (int o = tid; o < 16*384; o += 256){
      int r = o / 384, n = o - (o/384)*384;
      long row = rowBase + r;
      if (row >= NROW) continue;
      float acc = 0.f;
      if (n < 192){
        #pragma unroll
        for (int f = 0; f < 10; ++f) acc += xs[r][f]*wP[f][n];
        g_P[row*192 + n] = acc;
      } else {
        int nc = n - 192;
        #pragma unroll
        for (int f = 0; f < 10; ++f) acc += xs[r][f]*wQ[f][nc];
        g_Qbf[row*192 + nc] = __float2bfloat16(acc);
      }
    }
  }
}

// ---------------- fused edge-compute + CSR aggregate, XCD-swizzled rows, unroll x8 ----------------
__global__ __launch_bounds__(192) void k_aggedge(const void* __restrict__ w1cB, long w1cO,
                                                 const void* __restrict__ b1B, long b1O){
  int o = blockIdx.x;            // 6552
  int t = o & 7, s = o >> 3;     // s in 0..818
  int bk = t >> 1;               // 0..3
  int row = bk*S_ + 2*s + (t & 1);   // bijective over NROW
  int col = threadIdx.x;         // 192
  int i = row - bk*S_, b = bk >> 1;
  int off = g_off[b*(S_+1)+i];
  int deg = g_off[b*(S_+1)+i+1] - off;
  float w0 = LD(w1cB, w1cO+col),       w1v = LD(w1cB, w1cO+H_+col);
  float w2v = LD(w1cB, w1cO+2*H_+col), w3v = LD(w1cB, w1cO+3*H_+col);
  float base = g_P[(size_t)row*H_ + col] + LD(b1B, b1O+col);
  const int* lst = g_list + b*E_ + off;
  const bf* Q = g_Qbf + (size_t)bk*S_*H_;
  const float* EA = g_ea + (size_t)b*E_*4;
  float acc = 0.f;
  int d = 0;
  for (; d + 8 <= deg; d += 8){
    int e[8];
    #pragma unroll
    for (int u = 0; u < 8; ++u) e[u] = lst[d+u];
    float4 a[8];
    #pragma unroll
    for (int u = 0; u < 8; ++u) a[u] = *reinterpret_cast<const float4*>(EA + (size_t)e[u]*4);
    float qv[8];
    #pragma unroll
    for (int u = 0; u < 8; ++u) qv[u] = bf2f(Q[(size_t)(e[u]>>4)*H_ + col]);
    #pragma unroll
    for (int u = 0; u < 8; ++u)
      acc += gelu_f(base + qv[u] + a[u].x*w0 + a[u].y*w1v + a[u].z*w2v + a[u].w*w3v);
  }
  for (; d + 4 <= deg; d += 4){
    int e0 = lst[d], e1 = lst[d+1], e2 = lst[d+2], e3 = lst[d+3];
    float4 a0 = *reinterpret_cast<const float4*>(EA + (size_t)e0*4);
    float4 a1 = *reinterpret_cast<const float4*>(EA + (size_t)e1*4);
    float4 a2 = *reinterpret_cast<const float4*>(EA + (size_t)e2*4);
    float4 a3 = *reinterpret_cast<const float4*>(EA + (size_t)e3*4);
    float q0 = bf2f(Q[(size_t)(e0>>4)*H_ + col]);
    float q1 = bf2f(Q[(size_t)(e1>>4)*H_ + col]);
    float q2 = bf2f(Q[(size_t)(e2>>4)*H_ + col]);
    float q3 = bf2f(Q[(size_t)(e3>>4)*H_ + col]);
    acc += gelu_f(base + q0 + a0.x*w0 + a0.y*w1v + a0.z*w2v + a0.w*w3v);
    acc += gelu_f(base + q1 + a1.x*w0 + a1.y*w1v + a1.z*w2v + a1.w*w3v);
    acc += gelu_f(base + q2 + a2.x*w0 + a2.y*w1v + a2.z*w2v + a2.w*w3v);
    acc += gelu_f(base + q3 + a3.x*w0 + a3.y*w1v + a3.z*w2v + a3.w*w3v);
  }
  for (; d < deg; ++d){
    int e = lst[d];
    float4 a = *reinterpret_cast<const float4*>(EA + (size_t)e*4);
    float qv = bf2f(Q[(size_t)(e>>4)*H_ + col]);
    acc += gelu_f(base + qv + a.x*w0 + a.y*w1v + a.z*w2v + a.w*w3v);
  }
  g_abf[(size_t)row*H_ + col] = __float2bfloat16(acc);
}

// ---------------- fused: m2 GEMM + deg*b2 + LN + residual + {next-layer PQ GEMM | full head} ----------------
template<int RES, int DOPQ, int DOHEAD>
__global__ __launch_bounds__(512) void k_lnpq(const void* __restrict__ biasB, long biasO,
                                              const void* __restrict__ gB, long gO,
                                              const void* __restrict__ beB, long beO,
                                              int bOff, int pqOff,
                                              const void* __restrict__ hg, const void* __restrict__ hbe,
                                              const void* __restrict__ hb1, const void* __restrict__ hw2,
                                              const void* __restrict__ hb2, const void* __restrict__ ubase,
                                              const void* __restrict__ air, float* __restrict__ out,
                                              int M){
  const bf* A  = g_abf;
  const bf* Bp = g_w2p + bOff;
  int tid = threadIdx.x;
  int wv = tid >> 6, lane = tid & 63;
  int q = lane >> 4, l16 = lane & 15;
  long rowBase = (long)blockIdx.x * 16;
  __shared__ float tile[16][200];
  __shared__ bf    ybf[16][200];
  __shared__ float srow[16], rrow[16];
  // phase A: 12 col-tiles over 8 waves (waves 0-3 take 2, waves 4-7 take 1)
  {
    f32x4 acc[2];
    acc[0] = (f32x4){0.f,0.f,0.f,0.f};
    acc[1] = (f32x4){0.f,0.f,0.f,0.f};
    #pragma unroll
    for (int t = 0; t < 6; ++t){
      int kof = t*32 + q*8;
      long r = rowBase + l16; if (r >= M) r = M-1;
      bf16x8 af = *reinterpret_cast<const bf16x8*>(A + r*192 + kof);
      #pragma unroll
      for (int jj = 0; jj < 2; ++jj){
        int j = wv + jj*8;
        if (j < 12){
          int n = j*16 + l16;
          bf16x8 bfr = *reinterpret_cast<const bf16x8*>(Bp + (((t*4+q)*192 + n)*8));
          acc[jj] = __builtin_amdgcn_mfma_f32_16x16x32_bf16(af, bfr, acc[jj], 0,0,0);
        }
      }
    }
    float degf[4];
    #pragma unroll
    for (int r = 0; r < 4; ++r){
      int lr = q*4 + r;
      long row = rowBase + lr;
      long rowc = (row < M) ? row : (M-1);
      int bk = (int)(rowc / S_); int i = (int)(rowc - (long)bk*S_); int b = bk >> 1;
      degf[r] = (float)(g_off[b*(S_+1)+i+1] - g_off[b*(S_+1)+i]);
    }
    #pragma unroll
    for (int jj = 0; jj < 2; ++jj){
      int j = wv + jj*8;
      if (j < 12){
        int col = j*16 + l16;
        float bb = LD(biasB, biasO + col);
        #pragma unroll
        for (int r = 0; r < 4; ++r){
          int lr = q*4 + r;
          tile[lr][col] = acc[jj][r] + degf[r]*bb;
        }
      }
    }
  }
  __syncthreads();
  // LN: 2 rows per wave, 32-lane groups
  {
    int lr = wv*2 + (lane >> 5);
    int k32 = lane & 31;
    float s = 0.f, qq = 0.f;
    #pragma unroll
    for (int c6 = 0; c6 < 6; ++c6){ float x = tile[lr][k32 + c6*32]; s += x; qq += x*x; }
    #pragma unroll
    for (int o = 1; o < 32; o <<= 1){ s += __shfl_xor(s,o,64); qq += __shfl_xor(qq,o,64); }
    if (k32 == 0){
      float mu = s*(1.f/H_);
      float var = qq*(1.f/H_) - mu*mu;
      srow[lr] = mu;
      rrow[lr] = rsqrtf(fmaxf(var, 0.f) + 1e-5f);
    }
  }
  __syncthreads();
  for (int o = tid; o < 16*192; o += 512){
    int lr = o / 192, col = o - (o/192)*192;
    long row = rowBase + lr;
    long rowc = (row < M) ? row : (M-1);
    float y = (tile[lr][col] - srow[lr])*rrow[lr]*LD(gB,gO+col) + LD(beB,beO+col);
    if (RES) y += g_h[rowc*192 + col];
    if (!DOHEAD){
      if (row < M) g_h[row*192 + col] = y;
      ybf[lr][col] = __float2bfloat16(y);
    } else {
      tile[lr][col] = y;   // final h (fp32), in-place per-element
    }
  }
  if (DOPQ){
    __syncthreads();
    const bf* Bq = g_wcp + pqOff;
    f32x4 acc2[3];
    #pragma unroll
    for (int jj = 0; jj < 3; ++jj) acc2[jj] = (f32x4){0.f,0.f,0.f,0.f};
    #pragma unroll
    for (int t = 0; t < 6; ++t){
      int kof = t*32 + q*8;
      bf16x8 af = *reinterpret_cast<const bf16x8*>(&ybf[l16][kof]);
      #pragma unroll
      for (int jj = 0; jj < 3; ++jj){
        int n = (wv*3 + jj)*16 + l16;
        bf16x8 bfr = *reinterpret_cast<const bf16x8*>(Bq + (((t*4+q)*384 + n)*8));
        acc2[jj] = __builtin_amdgcn_mfma_f32_16x16x32_bf16(af, bfr, acc2[jj], 0,0,0);
      }
    }
    #pragma unroll
    for (int jj = 0; jj < 3; ++jj){
      int col = (wv*3 + jj)*16 + l16;
      #pragma unroll
      for (int r = 0; r < 4; ++r){
        long row = rowBase + q*4 + r;
        if (row < M){
          float v = acc2[jj][r];
          if (col < 192) g_P[row*192 + col] = v;
          else           g_Qbf[row*192 + (col-192)] = __float2bfloat16(v);
        }
      }
    }
  }
  if (DOHEAD){
    __syncthreads();
    // head LN over final h (fp32 in tile), 2 rows/wave, 32-lane groups
    {
      int lr = wv*2 + (lane >> 5);
      int k32 = lane & 31;
      float s = 0.f, qq = 0.f;
      #pragma unroll
      for (int c6 = 0; c6 < 6; ++c6){ float x = tile[lr][k32 + c6*32]; s += x; qq += x*x; }
      #pragma unroll
      for (int o = 1; o < 32; o <<= 1){ s += __shfl_xor(s,o,64); qq += __shfl_xor(qq,o,64); }
      if (k32 == 0){
        float mu = s*(1.f/H_);
        float var = qq*(1.f/H_) - mu*mu;
        srow[lr] = mu;
        rrow[lr] = rsqrtf(fmaxf(var, 0.f) + 1e-5f);
      }
    }
    __syncthreads();
    for (int o = tid; o < 16*192; o += 512){
      int lr = o / 192, col = o - (o/192)*192;
      ybf[lr][col] = __float2bfloat16((tile[lr][col] - srow[lr])*rrow[lr]*LD(hg,col) + LD(hbe,col));
    }
    __syncthreads();
    // head GEMM: hh @ hw1 (pre-packed at w2p slot 10), gelu into tile
    {
      const bf* Bh = g_w2p + 10*H_*H_;
      f32x4 hacc[2];
      hacc[0] = (f32x4){0.f,0.f,0.f,0.f};
      hacc[1] = (f32x4){0.f,0.f,0.f,0.f};
      #pragma unroll
      for (int t = 0; t < 6; ++t){
        int kof = t*32 + q*8;
        bf16x8 af = *reinterpret_cast<const bf16x8*>(&ybf[l16][kof]);
        #pragma unroll
        for (int jj = 0; jj < 2; ++jj){
          int j = wv + jj*8;
          if (j < 12){
            int n = j*16 + l16;
            bf16x8 bfr = *reinterpret_cast<const bf16x8*>(Bh + (((t*4+q)*192 + n)*8));
            hacc[jj] = __builtin_amdgcn_mfma_f32_16x16x32_bf16(af, bfr, hacc[jj], 0,0,0);
          }
        }
      }
      #pragma unroll
      for (int jj = 0; jj < 2; ++jj){
        int j = wv + jj*8;
        if (j < 12){
          int col = j*16 + l16;
          float bb = LD(hb1, col);
          #pragma unroll
          for (int r = 0; r < 4; ++r){
            int lr = q*4 + r;
            tile[lr][col] = gelu_f(hacc[jj][r] + bb);
          }
        }
      }
    }
    __syncthreads();
    // final 192x3 projection + masked scatter: 2 rows/wave, 32 lanes/row
    {
      int lr = wv*2 + (lane >> 5);
      int k32 = lane & 31;
      float p0 = 0.f, p1 = 0.f, p2 = 0.f;
      #pragma unroll
      for (int c6 = 0; c6 < 6; ++c6){
        int col = k32 + c6*32;
        float tv = tile[lr][col];
        p0 += tv*LD(hw2, col*3+0);
        p1 += tv*LD(hw2, col*3+1);
        p2 += tv*LD(hw2, col*3+2);
      }
      #pragma unroll
      for (int o = 1; o < 32; o <<= 1){
        p0 += __shfl_xor(p0,o,64);
        p1 += __shfl_xor(p1,o,64);
        p2 += __shfl_xor(p2,o,64);
      }
      if (k32 == 0){
        long row = rowBase + lr;
        if (row < M){
          int bk = (int)(row / S_), s = (int)(row - (long)bk*S_), b = bk >> 1;
          float msk = g_masksel[b*S_+s];
          int node = g_topidx[b*S_+s];
          float am = 1.f - LD(air, b*NN_+node);
          float d0 = p0 + LD(hb2,0), d1 = p1 + LD(hb2,1), d2 = p2 + LD(hb2,2);
          long oi = ((long)bk*NN_ + node)*3;
          out[oi+0] = (LD(ubase, oi+0) + d0*msk)*am;
          out[oi+1] = (LD(ubase, oi+1) + d1*msk)*am;
          out[oi+2] = (LD(ubase, oi+2) + d2*msk)*am;
        }
      }
    }
  }
}

extern "C" void kernel_launch(void* const* d_in, const int* in_sizes, int n_in,
                              void* d_out, int out_size, void* d_ws, size_t ws_size,
                              hipStream_t stream) {
  (void)in_sizes; (void)n_in; (void)d_ws; (void)ws_size; (void)out_size;
  const void* u_base = d_in[0];
  const void* pos    = d_in[1];
  const void* vel    = d_in[2];
  const void* air    = d_in[3];
  const void* c0w1   = d_in[4];
  const void* c0b1   = d_in[5];
  const void* c0w2   = d_in[6];
  const void* c0b2   = d_in[7];
  const void* c0g    = d_in[8];
  const void* c0be   = d_in[9];
  const void* cw1    = d_in[10];
  const void* cb1    = d_in[11];
  const void* cw2    = d_in[12];
  const void* cb2    = d_in[13];
  const void* cg     = d_in[14];
  const void* cbe    = d_in[15];
  const void* hg     = d_in[16];
  const void* hbe    = d_in[17];
  const void* hw1    = d_in[18];
  const void* hb1    = d_in[19];
  const void* hw2    = d_in[20];
  const void* hb2    = d_in[21];
  float* out = (float*)d_out;

  k_var<<<dim3(16, B_), 256, 0, stream>>>(vel, u_base, pos);
  k_rank<<<dim3(NN_/4, B_), 256, 0, stream>>>(pos);
  k_knngather<<<dim3(GATH_BLKS + (S_+3)/4, B_), 256, 0, stream>>>(pos, u_base, vel, air);
  k_scan<<<B_, 1024, 0, stream>>>();
  k_packall<<<PW2_BLKS + PWC_BLKS + INIT_BLKS + FILL_BLKS + PROJ_BLKS, 256, 0, stream>>>(
      c0w2, cw2, hw1, cw1, u_base, air, out, c0w1);

  const int GN16 = (NROW + 15) / 16;   // 410
  for (int l = 0; l < 10; ++l){
    long w1cO = (l == 0) ? 20L*H_ : ((long)(l-1)*388 + 384)*H_;
    const void* w1cB = (l == 0) ? c0w1 : cw1;
    long lOff = (l == 0) ? 0 : (long)(l-1)*H_;
    const void* b1B = (l == 0) ? c0b1 : cb1;
    k_aggedge<<<NROW, 192, 0, stream>>>(w1cB, w1cO, b1B, lOff);

    const void* b2B = (l == 0) ? c0b2 : cb2;
    const void* gB  = (l == 0) ? c0g  : cg;
    const void* beB = (l == 0) ? c0be : cbe;
    if (l == 0)
      k_lnpq<0,1,0><<<GN16, 512, 0, stream>>>(b2B, lOff, gB, lOff, beB, lOff, 0,        0,
                                              hg, hbe, hb1, hw2, hb2, u_base, air, out, NROW);
    else if (l < 9)
      k_lnpq<1,1,0><<<GN16, 512, 0, stream>>>(b2B, lOff, gB, lOff, beB, lOff, l*H_*H_, l*H_*384,
                                              hg, hbe, hb1, hw2, hb2, u_base, air, out, NROW);
    else
      k_lnpq<1,0,1><<<GN16, 512, 0, stream>>>(b2B, lOff, gB, lOff, beB, lOff, l*H_*H_, 0,
                                              hg, hbe, hb1, hw2, hb2, u_base, air, out, NROW);
  }
}